// Round 2
// baseline (6226.428 us; speedup 1.0000x reference)
//
#include <hip/hip_runtime.h>
#include <hip/hip_fp16.h>
#include <cmath>

typedef _Float16 f16;
typedef _Float16 f16x8 __attribute__((ext_vector_type(8)));
typedef float f32x4 __attribute__((ext_vector_type(4)));

constexpr int B = 128, T = 64, S = 80, H = 512;
constexpr int BH = B * H;      // 65536
constexpr int NWG = 256;

#define LB256 __launch_bounds__(256)

// ---------------------------------------------------------------------------
// grid barrier: release-RMW arrival (flushes dirty L2 to coherence point),
// relaxed spin, full fence on exit (invalidates stale L1/L2). All NWG WGs
// are co-resident (grid == 256 <= #CUs, any packing still fits).
__device__ __forceinline__ void gbar(unsigned* ctr) {
    __syncthreads();
    if (threadIdx.x == 0) {
        __hip_atomic_fetch_add(ctr, 1u, __ATOMIC_SEQ_CST, __HIP_MEMORY_SCOPE_AGENT);
        unsigned v;
        do {
            __builtin_amdgcn_s_sleep(1);
            v = __hip_atomic_load(ctr, __ATOMIC_RELAXED, __HIP_MEMORY_SCOPE_AGENT);
        } while (v < (unsigned)NWG);
        __threadfence();
    }
    __syncthreads();
}

// ---------------------------------------------------------------------------
// setup: pack weights f16, biases, transpose W_in, zero barriers, init state
__global__ LB256 void prep_all(
    const float* __restrict__ Wih0, const float* __restrict__ Whh0,
    const float* __restrict__ Wih1, const float* __restrict__ Whh1,
    const float* __restrict__ Wout, const float* __restrict__ Win,
    const float* __restrict__ bih0, const float* __restrict__ bhh0,
    const float* __restrict__ bih1, const float* __restrict__ bhh1,
    const float* __restrict__ h0, const float* __restrict__ c0,
    f16* __restrict__ WB0p, f16* __restrict__ WB1p, f16* __restrict__ WoutB,
    f16* __restrict__ WinTf, float* __restrict__ bsum0, float* __restrict__ bsum1,
    f16* __restrict__ h0buf, f16* __restrict__ h1buf,
    float* __restrict__ c0s, float* __restrict__ c1s,
    f16* __restrict__ xprev, unsigned* __restrict__ bars)
{
    int stride = gridDim.x * blockDim.x;
    int idx = blockIdx.x * blockDim.x + threadIdx.x;
    // WB0p[n][k]: k<1024 -> Wih0[n][k], else Whh0[n][k-1024]  (K=1536)
    for (int i = idx; i < 2048 * 1536; i += stride) {
        int n = i / 1536, k = i - n * 1536;
        float v = (k < 1024) ? Wih0[n * 1024 + k] : Whh0[n * 512 + (k - 1024)];
        WB0p[i] = (f16)v;
    }
    // WB1p[n][k]: k<512 -> Wih1, else Whh1   (K=1024)
    for (int i = idx; i < 2048 * 1024; i += stride) {
        int n = i >> 10, k = i & 1023;
        float v = (k < 512) ? Wih1[n * 512 + k] : Whh1[n * 512 + (k - 512)];
        WB1p[i] = (f16)v;
    }
    for (int i = idx; i < 512 * 1024; i += stride) WoutB[i] = (f16)Wout[i];
    // WinTf[k][j] = Win[j][k]
    for (int i = idx; i < 512 * 512; i += stride) {
        int k = i >> 9, j = i & 511;
        WinTf[i] = (f16)Win[j * 512 + k];
    }
    for (int i = idx; i < 2048; i += stride) {
        bsum0[i] = bih0[i] + bhh0[i];
        bsum1[i] = bih1[i] + bhh1[i];
    }
    for (int i = idx; i < BH; i += stride) {
        h0buf[i] = (f16)h0[i];          // parity 0
        h1buf[i] = (f16)h0[BH + i];
        c0s[i] = c0[i];
        c1s[i] = c0[BH + i];
        xprev[i] = (f16)0.f;
    }
    for (int i = idx; i < 512; i += stride) bars[i] = 0u;
}

__global__ LB256 void prep_emb(const int* __restrict__ tokens,
                               const float* __restrict__ embtab,
                               f16* __restrict__ embf16)
{
    int stride = gridDim.x * blockDim.x;
    for (int i = blockIdx.x * blockDim.x + threadIdx.x; i < T * B * 512; i += stride) {
        int e = i & 511;
        int tb = i >> 9;
        int tok = tokens[tb];
        embf16[i] = (f16)embtab[(size_t)tok * 512 + e];
    }
}

// ctxW[m][n] = sum_j A32[m][j] * Wf[n][j]   (A fp32, W f16, out f16)
// grid (N/32, M/32), 256 thr (4 waves 2x2 of 16x16), K=512
__global__ LB256 void gemm_a32(const float* __restrict__ A32,
                               const f16* __restrict__ Wf,
                               f16* __restrict__ Cf)
{
    const int lane = threadIdx.x & 63;
    const int wave = threadIdx.x >> 6;
    const int quad = lane >> 4;
    const int wb = wave >> 1, wn = wave & 1;
    const int m = blockIdx.y * 32 + wb * 16 + (lane & 15);
    const int n = blockIdx.x * 32 + wn * 16 + (lane & 15);

    f32x4 acc = {0.f, 0.f, 0.f, 0.f};
    const float* ar = A32 + (size_t)m * 512;
    const f16* wr = Wf + (size_t)n * 512;
    #pragma unroll 4
    for (int i = 0; i < 16; ++i) {
        int k = i * 32 + quad * 8;
        float4 u0 = *(const float4*)(ar + k);
        float4 u1 = *(const float4*)(ar + k + 4);
        f16x8 av = { (f16)u0.x, (f16)u0.y, (f16)u0.z, (f16)u0.w,
                     (f16)u1.x, (f16)u1.y, (f16)u1.z, (f16)u1.w };
        f16x8 wv = *(const f16x8*)(wr + k);
        acc = __builtin_amdgcn_mfma_f32_16x16x32_f16(av, wv, acc, 0, 0, 0);
    }
    const int col = blockIdx.x * 32 + wn * 16 + (lane & 15);
    #pragma unroll
    for (int r = 0; r < 4; ++r) {
        int row = blockIdx.y * 32 + wb * 16 + quad * 4 + r;
        Cf[(size_t)row * 512 + col] = (f16)acc[r];
    }
}

// ---------------------------------------------------------------------------
// persistent decoder: 256 WGs x 256 thr, whole T-loop inside, 4 barriers/step
__global__ LB256 void decoder_persist(
    const f16* __restrict__ embf16,   // [T][B][512]
    const f16* __restrict__ WB0p,     // [2048][1536]
    const f16* __restrict__ WB1p,     // [2048][1024]
    const f16* __restrict__ WoutB,    // [512][1024]
    const f16* __restrict__ ctxW,     // [B][S][512]
    const float* __restrict__ ctx,    // [B][S][512] fp32 (input)
    const float* __restrict__ bsum0, const float* __restrict__ bsum1,
    f16* __restrict__ h0buf, f16* __restrict__ h1buf,   // [2][B][512]
    f16* __restrict__ xprev, f16* __restrict__ wctx,    // [B][512]
    float* __restrict__ c0s, float* __restrict__ c1s,   // [B][512]
    unsigned* __restrict__ bars,
    float* __restrict__ out_outputs, float* __restrict__ out_attn,
    float* __restrict__ out_hT, float* __restrict__ out_cT)
{
    const int wg = blockIdx.x;
    const int tid = threadIdx.x;
    const int lane = tid & 63;
    const int wave = tid >> 6;
    const int quad = lane >> 4;
    const int m16 = lane & 15;

    // LDS: stage A X [16][1544] f16 (49408 B) + gbuf [4][16][17] f32 (4352 B)
    __shared__ __align__(16) char smem[49408 + 4352];
    f16 (*XA)[1544] = (f16 (*)[1544])smem;
    f16 (*XB)[1032] = (f16 (*)[1032])smem;    // stage B/D staging (33024 B)
    float (*gbuf)[16][17] = (float (*)[16][17])(smem + 49408);
    float* sc = (float*)smem;                 // stage C scores/probs (80 f32)

    const int gn = wg & 31;     // h-slice [gn*16, +16)
    const int gb = wg >> 5;     // b-slice [gb*16, +16)

    for (int t = 0; t < T; ++t) {
        const int rp = t & 1, wp = rp ^ 1;
        const f16* h0r = h0buf + rp * BH;
        f16*       h0w = h0buf + wp * BH;
        const f16* h1r = h1buf + rp * BH;
        f16*       h1w = h1buf + wp * BH;

        // ================= stage A: lstm0 =================
        {
            const f16* e = embf16 + (size_t)t * BH;
            const int b0 = gb * 16;
            for (int c = tid; c < 3072; c += 256) {     // 16 rows x 192 chunks
                int r = c / 192, k8 = (c - r * 192) * 8;
                const f16* src;
                if (k8 < 512)       src = e     + (b0 + r) * 512 + k8;
                else if (k8 < 1024) src = xprev + (b0 + r) * 512 + (k8 - 512);
                else                src = h0r   + (b0 + r) * 512 + (k8 - 1024);
                *(f16x8*)(&XA[r][k8]) = *(const f16x8*)src;
            }
            __syncthreads();

            f32x4 acc = {0.f, 0.f, 0.f, 0.f};
            const int nrow = wave * 512 + gn * 16 + m16;   // gate = wave
            const f16* wr = WB0p + (size_t)nrow * 1536;
            #pragma unroll 4
            for (int i = 0; i < 48; ++i) {
                int k = i * 32 + quad * 8;
                f16x8 av = *(const f16x8*)(&XA[m16][k]);
                f16x8 wv = *(const f16x8*)(wr + k);
                acc = __builtin_amdgcn_mfma_f32_16x16x32_f16(av, wv, acc, 0, 0, 0);
            }
            #pragma unroll
            for (int r = 0; r < 4; ++r) gbuf[wave][quad * 4 + r][m16] = acc[r];
            __syncthreads();

            const int b = tid >> 4, hh = tid & 15;
            const int h = gn * 16 + hh;
            const int gbl = (gb * 16 + b) * 512 + h;
            float zi = gbuf[0][b][hh] + bsum0[h];
            float zf = gbuf[1][b][hh] + bsum0[512 + h];
            float zg = gbuf[2][b][hh] + bsum0[1024 + h];
            float zo = gbuf[3][b][hh] + bsum0[1536 + h];
            float ig = 1.f / (1.f + expf(-zi));
            float fg = 1.f / (1.f + expf(-zf));
            float og = 1.f / (1.f + expf(-zo));
            float gg = tanhf(zg);
            float c = fg * c0s[gbl] + ig * gg;
            c0s[gbl] = c;
            h0w[gbl] = (f16)(og * tanhf(c));
        }
        gbar(&bars[t * 4 + 0]);

        // ================= stage B: lstm1 =================
        {
            const int b0 = gb * 16;
            for (int c = tid; c < 2048; c += 256) {     // 16 rows x 128 chunks
                int r = c >> 7, k8 = (c & 127) * 8;
                const f16* src = (k8 < 512) ? (h0w + (b0 + r) * 512 + k8)
                                            : (h1r + (b0 + r) * 512 + (k8 - 512));
                *(f16x8*)(&XB[r][k8]) = *(const f16x8*)src;
            }
            __syncthreads();

            f32x4 acc = {0.f, 0.f, 0.f, 0.f};
            const int nrow = wave * 512 + gn * 16 + m16;
            const f16* wr = WB1p + (size_t)nrow * 1024;
            #pragma unroll 4
            for (int i = 0; i < 32; ++i) {
                int k = i * 32 + quad * 8;
                f16x8 av = *(const f16x8*)(&XB[m16][k]);
                f16x8 wv = *(const f16x8*)(wr + k);
                acc = __builtin_amdgcn_mfma_f32_16x16x32_f16(av, wv, acc, 0, 0, 0);
            }
            #pragma unroll
            for (int r = 0; r < 4; ++r) gbuf[wave][quad * 4 + r][m16] = acc[r];
            __syncthreads();

            const int b = tid >> 4, hh = tid & 15;
            const int h = gn * 16 + hh;
            const int gbl = (gb * 16 + b) * 512 + h;
            float zi = gbuf[0][b][hh] + bsum1[h];
            float zf = gbuf[1][b][hh] + bsum1[512 + h];
            float zg = gbuf[2][b][hh] + bsum1[1024 + h];
            float zo = gbuf[3][b][hh] + bsum1[1536 + h];
            float ig = 1.f / (1.f + expf(-zi));
            float fg = 1.f / (1.f + expf(-zf));
            float og = 1.f / (1.f + expf(-zo));
            float gg = tanhf(zg);
            float c = fg * c1s[gbl] + ig * gg;
            c1s[gbl] = c;
            h1w[gbl] = (f16)(og * tanhf(c));
        }
        gbar(&bars[t * 4 + 1]);

        // ================= stage C: attention (WGs 0..127, one per b) ======
        if (wg < 128) {
            const f16* hr = h1w + wg * 512;
            // scores via MFMA: 5 m-tiles of 16 s-rows, K=512
            for (int tile = wave; tile < 5; tile += 4) {
                f32x4 a = {0.f, 0.f, 0.f, 0.f};
                const f16* ar = ctxW + ((size_t)wg * 80 + tile * 16 + m16) * 512;
                #pragma unroll 4
                for (int i = 0; i < 16; ++i) {
                    int k = i * 32 + quad * 8;
                    f16x8 av = *(const f16x8*)(ar + k);
                    f16x8 hv = *(const f16x8*)(hr + k);
                    a = __builtin_amdgcn_mfma_f32_16x16x32_f16(av, hv, a, 0, 0, 0);
                }
                if (m16 == 0) {
                    #pragma unroll
                    for (int r = 0; r < 4; ++r) sc[tile * 16 + quad * 4 + r] = a[r];
                }
            }
            __syncthreads();
            if (wave == 0) {
                float e0 = sc[lane];
                float e1 = (lane < 16) ? sc[64 + lane] : -1e30f;
                float m = fmaxf(e0, e1);
                #pragma unroll
                for (int o = 32; o > 0; o >>= 1) m = fmaxf(m, __shfl_xor(m, o));
                float x0 = expf(e0 - m);
                float x1 = (lane < 16) ? expf(e1 - m) : 0.f;
                float su = x0 + x1;
                #pragma unroll
                for (int o = 32; o > 0; o >>= 1) su += __shfl_xor(su, o);
                float inv = 1.f / su;
                float p0 = x0 * inv;
                sc[lane] = p0;
                out_attn[((size_t)t * B + wg) * 80 + lane] = p0;
                if (lane < 16) {
                    float p1 = x1 * inv;
                    sc[64 + lane] = p1;
                    out_attn[((size_t)t * B + wg) * 80 + 64 + lane] = p1;
                }
            }
            __syncthreads();
            // wctx[h] = sum_s p[s] * ctx[b][s][h]  (fp32)
            const float* cb = ctx + (size_t)wg * 80 * 512;
            for (int h = tid; h < 512; h += 256) {
                float a = 0.f;
                #pragma unroll 8
                for (int s = 0; s < 80; ++s) a += sc[s] * cb[s * 512 + h];
                wctx[wg * 512 + h] = (f16)a;
            }
        }
        gbar(&bars[t * 4 + 2]);

        // ================= stage D: out GEMM (WGs 0..63) =================
        if (wg < 64) {
            const int gn2 = wg & 7;      // n-slice [gn2*64, +64)
            const int gb2 = wg >> 3;     // b-slice [gb2*16, +16)
            const int b0 = gb2 * 16;
            for (int c = tid; c < 2048; c += 256) {
                int r = c >> 7, k8 = (c & 127) * 8;
                const f16* src = (k8 < 512) ? (wctx + (b0 + r) * 512 + k8)
                                            : (h1w  + (b0 + r) * 512 + (k8 - 512));
                *(f16x8*)(&XB[r][k8]) = *(const f16x8*)src;
            }
            __syncthreads();

            f32x4 acc = {0.f, 0.f, 0.f, 0.f};
            const int nrow = gn2 * 64 + wave * 16 + m16;
            const f16* wr = WoutB + (size_t)nrow * 1024;
            #pragma unroll 4
            for (int i = 0; i < 32; ++i) {
                int k = i * 32 + quad * 8;
                f16x8 av = *(const f16x8*)(&XB[m16][k]);
                f16x8 wv = *(const f16x8*)(wr + k);
                acc = __builtin_amdgcn_mfma_f32_16x16x32_f16(av, wv, acc, 0, 0, 0);
            }
            const int col = gn2 * 64 + wave * 16 + m16;
            #pragma unroll
            for (int r = 0; r < 4; ++r) {
                int row = b0 + quad * 4 + r;
                float v = tanhf(acc[r]);
                out_outputs[(size_t)t * BH + row * 512 + col] = v;
                xprev[row * 512 + col] = (f16)v;
            }
        }
        gbar(&bars[t * 4 + 3]);
    }

    // epilogue: final h (parity 0 after 64 steps) and c
    {
        int i = wg * 256 + tid;      // exactly BH threads
        out_hT[i] = (float)h0buf[i];
        out_hT[BH + i] = (float)h1buf[i];
        out_cT[i] = c0s[i];
        out_cT[BH + i] = c1s[i];
    }
}

// ---------------------------------------------------------------------------
extern "C" void kernel_launch(void* const* d_in, const int* in_sizes, int n_in,
                              void* d_out, int out_size, void* d_ws, size_t ws_size,
                              hipStream_t stream)
{
    const int*   tokens  = (const int*)  d_in[0];
    const float* h0      = (const float*)d_in[1];
    const float* c0      = (const float*)d_in[2];
    const float* context = (const float*)d_in[3];
    const float* embtab  = (const float*)d_in[4];
    const float* Wih0    = (const float*)d_in[5];
    const float* Whh0    = (const float*)d_in[6];
    const float* bih0    = (const float*)d_in[7];
    const float* bhh0    = (const float*)d_in[8];
    const float* Wih1    = (const float*)d_in[9];
    const float* Whh1    = (const float*)d_in[10];
    const float* bih1    = (const float*)d_in[11];
    const float* bhh1    = (const float*)d_in[12];
    const float* Win     = (const float*)d_in[13];
    const float* Wout    = (const float*)d_in[14];

    float* outF        = (float*)d_out;
    float* out_outputs = outF;
    float* out_hT      = outF + (size_t)T * BH;
    float* out_cT      = out_hT + 2 * BH;
    float* out_attn    = out_cT + 2 * BH;

    char* w = (char*)d_ws;
    auto alloc = [&](size_t bytes) {
        char* p = w;
        w += (bytes + 255) & ~(size_t)255;
        return p;
    };
    f16*      WB0p   = (f16*)     alloc((size_t)2048 * 1536 * 2);
    f16*      WB1p   = (f16*)     alloc((size_t)2048 * 1024 * 2);
    f16*      WoutB  = (f16*)     alloc((size_t)512 * 1024 * 2);
    f16*      WinTf  = (f16*)     alloc((size_t)512 * 512 * 2);
    f16*      embf16 = (f16*)     alloc((size_t)T * B * 512 * 2);
    f16*      ctxWb  = (f16*)     alloc((size_t)B * S * 512 * 2);
    float*    bsum0  = (float*)   alloc(2048 * 4);
    float*    bsum1  = (float*)   alloc(2048 * 4);
    f16*      h0buf  = (f16*)     alloc((size_t)2 * BH * 2);
    f16*      h1buf  = (f16*)     alloc((size_t)2 * BH * 2);
    f16*      xprev  = (f16*)     alloc((size_t)BH * 2);
    f16*      wctxb  = (f16*)     alloc((size_t)BH * 2);
    float*    c0s    = (float*)   alloc((size_t)BH * 4);
    float*    c1s    = (float*)   alloc((size_t)BH * 4);
    unsigned* bars   = (unsigned*)alloc(512 * 4);

    prep_all<<<1024, 256, 0, stream>>>(Wih0, Whh0, Wih1, Whh1, Wout, Win,
                                       bih0, bhh0, bih1, bhh1, h0, c0,
                                       WB0p, WB1p, WoutB, WinTf, bsum0, bsum1,
                                       h0buf, h1buf, c0s, c1s, xprev, bars);
    prep_emb<<<2048, 256, 0, stream>>>(tokens, embtab, embf16);
    // ctxW[b*S+s][k] = sum_j context[b][s][j] * Win[j][k]
    gemm_a32<<<dim3(16, 320), 256, 0, stream>>>(context, WinTf, ctxWb);

    decoder_persist<<<NWG, 256, 0, stream>>>(
        embf16, WB0p, WB1p, WoutB, ctxWb, context, bsum0, bsum1,
        h0buf, h1buf, xprev, wctxb, c0s, c1s, bars,
        out_outputs, out_attn, out_hT, out_cT);
}

// Round 3
// 5918.523 us; speedup vs baseline: 1.0520x; 1.0520x over previous
//
#include <hip/hip_runtime.h>
#include <hip/hip_fp16.h>
#include <cmath>

typedef _Float16 f16;
typedef _Float16 f16x8 __attribute__((ext_vector_type(8)));
typedef float f32x4 __attribute__((ext_vector_type(4)));
typedef unsigned long long u64;

constexpr int B = 128, T = 64, S = 80, H = 512;
constexpr int BH = B * H;      // 65536
constexpr int NWG = 256;

#define LB256 __launch_bounds__(256)
#define MFMA16(a, b, c) __builtin_amdgcn_mfma_f32_16x16x32_f16(a, b, c, 0, 0, 0)

// ---- agent-scope (cross-XCD coherent, L1/L2-bypassing) accessors ----------
__device__ __forceinline__ f16x8 aload16(const f16* p) {
    union { u64 u[2]; f16x8 v; } x;
    x.u[0] = __hip_atomic_load((const u64*)p,     __ATOMIC_RELAXED, __HIP_MEMORY_SCOPE_AGENT);
    x.u[1] = __hip_atomic_load((const u64*)p + 1, __ATOMIC_RELAXED, __HIP_MEMORY_SCOPE_AGENT);
    return x.v;
}
__device__ __forceinline__ u64 aload8(const void* p) {
    return __hip_atomic_load((const u64*)p, __ATOMIC_RELAXED, __HIP_MEMORY_SCOPE_AGENT);
}
__device__ __forceinline__ void astore8(void* p, u64 v) {
    __hip_atomic_store((u64*)p, v, __ATOMIC_RELAXED, __HIP_MEMORY_SCOPE_AGENT);
}
__device__ __forceinline__ void astore4(void* p, unsigned v) {
    __hip_atomic_store((unsigned*)p, v, __ATOMIC_RELAXED, __HIP_MEMORY_SCOPE_AGENT);
}

// ---- barrier pieces: NO cache-invalidating fence --------------------------
// __syncthreads drains each wave's vmcnt (compiler emits s_waitcnt vmcnt(0)
// before s_barrier), so all the WG's write-through stores are at the
// coherence point before thread 0's release-increment.
__device__ __forceinline__ void arrive(unsigned* c) {
    __syncthreads();
    if (threadIdx.x == 0)
        __hip_atomic_fetch_add(c, 1u, __ATOMIC_RELEASE, __HIP_MEMORY_SCOPE_AGENT);
}
__device__ __forceinline__ void waitc(unsigned* c, unsigned tgt) {
    if (threadIdx.x == 0) {
        while (__hip_atomic_load(c, __ATOMIC_RELAXED, __HIP_MEMORY_SCOPE_AGENT) < tgt)
            __builtin_amdgcn_s_sleep(2);
    }
    __syncthreads();
}

// ---------------------------------------------------------------------------
// setup: pack weights (gate-interleaved row' = n*4+g), biases, init state
__global__ LB256 void prep_all(
    const float* __restrict__ Wih0, const float* __restrict__ Whh0,
    const float* __restrict__ Wih1, const float* __restrict__ Whh1,
    const float* __restrict__ Wout, const float* __restrict__ Win,
    const float* __restrict__ bih0, const float* __restrict__ bhh0,
    const float* __restrict__ bih1, const float* __restrict__ bhh1,
    const float* __restrict__ h0, const float* __restrict__ c0,
    f16* __restrict__ WB0p, f16* __restrict__ WB1p,
    f16* __restrict__ WoutRf, f16* __restrict__ WcatT,
    float* __restrict__ bsum0, float* __restrict__ bsum1,
    f16* __restrict__ h0buf, f16* __restrict__ h1buf,
    f16* __restrict__ xprev, unsigned* __restrict__ bars)
{
    int stride = gridDim.x * blockDim.x;
    int idx = blockIdx.x * blockDim.x + threadIdx.x;
    // WB0p[row'][k], row'=n*4+g, K=1536: k<1024 Wih0[g*512+n][k] else Whh0[..][k-1024]
    for (int i = idx; i < 2048 * 1536; i += stride) {
        int rp = i / 1536, k = i - rp * 1536;
        int n = rp >> 2, g = rp & 3, src = g * 512 + n;
        float v = (k < 1024) ? Wih0[src * 1024 + k] : Whh0[src * 512 + (k - 1024)];
        WB0p[i] = (f16)v;
    }
    // WB1p[row'][k], K=1024: k<512 Wih1 else Whh1
    for (int i = idx; i < 2048 * 1024; i += stride) {
        int rp = i >> 10, k = i & 1023;
        int n = rp >> 2, g = rp & 3, src = g * 512 + n;
        float v = (k < 512) ? Wih1[src * 512 + k] : Whh1[src * 512 + (k - 512)];
        WB1p[i] = (f16)v;
    }
    // WoutRf[n][k] = W_out[n][512+k]
    for (int i = idx; i < 512 * 512; i += stride) {
        int n = i >> 9, k = i & 511;
        WoutRf[i] = (f16)Wout[n * 1024 + 512 + k];
    }
    // WcatT rows 0-511: Win^T (WcatT[r][k]=Win[k][r]); rows 512-1023: W_out left half
    for (int i = idx; i < 1024 * 512; i += stride) {
        int r = i >> 9, k = i & 511;
        float v = (r < 512) ? Win[k * 512 + r] : Wout[(r - 512) * 1024 + k];
        WcatT[i] = (f16)v;
    }
    for (int i = idx; i < 2048; i += stride) {
        bsum0[i] = bih0[i] + bhh0[i];
        bsum1[i] = bih1[i] + bhh1[i];
    }
    for (int i = idx; i < BH; i += stride) {
        h0buf[i] = (f16)h0[i];          // parity 0
        h1buf[i] = (f16)h0[BH + i];
        xprev[i] = (f16)0.f;
    }
    for (int i = idx; i < 256; i += stride) bars[i] = 0u;
}

__global__ LB256 void prep_emb(const int* __restrict__ tokens,
                               const float* __restrict__ embtab,
                               f16* __restrict__ embf16)
{
    int stride = gridDim.x * blockDim.x;
    for (int i = blockIdx.x * blockDim.x + threadIdx.x; i < T * B * 512; i += stride) {
        int e = i & 511;
        int tb = i >> 9;
        int tok = tokens[tb];
        embf16[i] = (f16)embtab[(size_t)tok * 512 + e];
    }
}

// ctxWV[m][j] = sum_k ctx_flat[m][k] * WcatT[j][k]  (out stride 1024)
// grid (1024/32, 10240/32), block 256 (4 waves 2x2 of 16x16), K=512
__global__ LB256 void gemm_ctx(const float* __restrict__ A32,
                               const f16* __restrict__ Wf,
                               f16* __restrict__ Cf)
{
    const int lane = threadIdx.x & 63;
    const int wave = threadIdx.x >> 6;
    const int quad = lane >> 4;
    const int wb = wave >> 1, wn = wave & 1;
    const int m = blockIdx.y * 32 + wb * 16 + (lane & 15);
    const int n = blockIdx.x * 32 + wn * 16 + (lane & 15);

    f32x4 acc = {0.f, 0.f, 0.f, 0.f};
    const float* ar = A32 + (size_t)m * 512;
    const f16* wr = Wf + (size_t)n * 512;
    #pragma unroll 4
    for (int i = 0; i < 16; ++i) {
        int k = i * 32 + quad * 8;
        float4 u0 = *(const float4*)(ar + k);
        float4 u1 = *(const float4*)(ar + k + 4);
        f16x8 av = { (f16)u0.x, (f16)u0.y, (f16)u0.z, (f16)u0.w,
                     (f16)u1.x, (f16)u1.y, (f16)u1.z, (f16)u1.w };
        f16x8 wv = *(const f16x8*)(wr + k);
        acc = MFMA16(av, wv, acc);
    }
    const int col = blockIdx.x * 32 + wn * 16 + (lane & 15);
    #pragma unroll
    for (int r = 0; r < 4; ++r) {
        int row = blockIdx.y * 32 + wb * 16 + quad * 4 + r;
        Cf[(size_t)row * 1024 + col] = (f16)acc[r];
    }
}

// ---------------------------------------------------------------------------
// persistent decoder: 256 WGs x 256 thr; weights LDS-resident; no cache fences
__global__ __launch_bounds__(256, 1) void decoder_persist(
    const f16* __restrict__ embf16,   // [T][B][512]
    const f16* __restrict__ WB0p,     // [2048][1536] gate-interleaved
    const f16* __restrict__ WB1p,     // [2048][1024]
    const f16* __restrict__ WoutRf,   // [512][512]
    const f16* __restrict__ ctxWV,    // [B*S][1024]: cols 0-511 ctxW, 512-1023 ctxV
    const float* __restrict__ bsum0, const float* __restrict__ bsum1,
    const float* __restrict__ c0in,   // [2][B][512] fp32 input
    f16* __restrict__ h0buf, f16* __restrict__ h1buf,   // [2][B][512]
    f16* __restrict__ xprev,                            // [B][512]
    unsigned* __restrict__ bars,
    float* __restrict__ out_outputs, float* __restrict__ out_attn,
    float* __restrict__ out_hT, float* __restrict__ out_cT)
{
    const int wg = blockIdx.x, tid = threadIdx.x;
    const int lane = tid & 63, wv_ = tid >> 6, quad = lane >> 4, m16 = lane & 15;
    const bool isA = (wg < 128);

    __shared__ f16 WL[16][1544];                 // 16 weight rows, pad+8 (2-way max)
    __shared__ float gbuf[4][2][16][17];
    __shared__ float scf[80], pp[80];
    __shared__ __align__(16) f16 h1s[512];
    __shared__ __align__(8)  f16 obuf[256];

    // ---- one-time: weights -> LDS ----
    {
        const f16* src = isA ? (WB0p + (size_t)wg * 16 * 1536)
                             : (WB1p + (size_t)(wg - 128) * 16 * 1024);
        const int K = isA ? 1536 : 1024;
        const int ck = K / 8;
        for (int i = tid; i < 16 * ck; i += 256) {
            int r = i / ck, k8 = (i - r * ck) * 8;
            *(f16x8*)&WL[r][k8] = *(const f16x8*)(src + (size_t)r * K + k8);
        }
    }
    // ---- cell ownership: thread owns (b=tid&127, n_l = (tid>>7)*2 + {0,1}) ----
    const int bb = tid & 127, jb = (tid >> 7) * 2;
    const int wrole = isA ? wg : (wg - 128);
    const int nbase = wrole * 4 + jb;
    float ca[2];
    float bias[2][4];
    {
        const float* bs = isA ? bsum0 : bsum1;
        const float* ci = c0in + (isA ? 0 : BH);
        #pragma unroll
        for (int j = 0; j < 2; ++j) {
            ca[j] = ci[bb * 512 + nbase + j];
            #pragma unroll
            for (int g = 0; g < 4; ++g) bias[j][g] = bs[g * 512 + nbase + j];
        }
    }
    // ---- attention role: pair (wg, wg^8) shares b (same XCD under %8 RR) ----
    const int cb = (wg >> 4) * 8 + (wg & 7);
    const int nh = (wg >> 3) & 1;
    __syncthreads();

    for (int t = 0; t < T; ++t) {
        const int rp = t & 1, wp = rp ^ 1;
        f16*       h0w = h0buf + wp * BH;
        const f16* h0r = h0buf + rp * BH;
        f16*       h1w = h1buf + wp * BH;
        const f16* h1r = h1buf + rp * BH;
        unsigned* bar1 = &bars[t * 3];
        unsigned* bar2 = bar1 + 1;
        unsigned* bar3 = bar1 + 2;

        if (isA) {
            // ============ phase A: lstm0 (gates [128 b x 16 rows], K=1536) ====
            const f16* e = embf16 + (size_t)t * BH;
            f32x4 ac0 = {0.f, 0.f, 0.f, 0.f}, ac1 = {0.f, 0.f, 0.f, 0.f};
            const int b0 = (wv_ * 32 + m16) * 512, b1 = b0 + 16 * 512;
            #pragma unroll
            for (int ks = 0; ks < 16; ++ks) {            // emb (cached)
                int k = ks * 32 + quad * 8;
                f16x8 w = *(const f16x8*)&WL[m16][k];
                f16x8 a0 = *(const f16x8*)(e + b0 + k);
                f16x8 a1 = *(const f16x8*)(e + b1 + k);
                ac0 = MFMA16(a0, w, ac0);
                ac1 = MFMA16(a1, w, ac1);
            }
            #pragma unroll
            for (int ks = 0; ks < 16; ++ks) {            // xprev (agent)
                int k = ks * 32 + quad * 8;
                f16x8 w = *(const f16x8*)&WL[m16][512 + k];
                f16x8 a0 = aload16(xprev + b0 + k);
                f16x8 a1 = aload16(xprev + b1 + k);
                ac0 = MFMA16(a0, w, ac0);
                ac1 = MFMA16(a1, w, ac1);
            }
            #pragma unroll
            for (int ks = 0; ks < 16; ++ks) {            // h0 prev (agent)
                int k = ks * 32 + quad * 8;
                f16x8 w = *(const f16x8*)&WL[m16][1024 + k];
                f16x8 a0 = aload16(h0r + b0 + k);
                f16x8 a1 = aload16(h0r + b1 + k);
                ac0 = MFMA16(a0, w, ac0);
                ac1 = MFMA16(a1, w, ac1);
            }
            #pragma unroll
            for (int r = 0; r < 4; ++r) {
                gbuf[wv_][0][quad * 4 + r][m16] = ac0[r];
                gbuf[wv_][1][quad * 4 + r][m16] = ac1[r];
            }
            __syncthreads();
            // cell
            const int v = bb >> 5, tau = (bb >> 4) & 1, row = bb & 15;
            float hv[2];
            #pragma unroll
            for (int j = 0; j < 2; ++j) {
                int c0l = (jb + j) * 4;
                float zi = gbuf[v][tau][row][c0l + 0] + bias[j][0];
                float zf = gbuf[v][tau][row][c0l + 1] + bias[j][1];
                float zg = gbuf[v][tau][row][c0l + 2] + bias[j][2];
                float zo = gbuf[v][tau][row][c0l + 3] + bias[j][3];
                float ig = 1.f / (1.f + expf(-zi));
                float fg = 1.f / (1.f + expf(-zf));
                float og = 1.f / (1.f + expf(-zo));
                float gg = tanhf(zg);
                float c = fg * ca[j] + ig * gg;
                ca[j] = c;
                hv[j] = og * tanhf(c);
            }
            union { f16 f[2]; unsigned u; } pk;
            pk.f[0] = (f16)hv[0]; pk.f[1] = (f16)hv[1];
            astore4(h0w + bb * 512 + nbase, pk.u);
            if (t == T - 1) {
                out_hT[bb * 512 + nbase]     = hv[0];
                out_hT[bb * 512 + nbase + 1] = hv[1];
                out_cT[bb * 512 + nbase]     = ca[0];
                out_cT[bb * 512 + nbase + 1] = ca[1];
            }
            arrive(bar1);
        } else {
            // ============ phase B: lstm1 (K=1024) ============
            waitc(bar1, 128);
            f32x4 ac0 = {0.f, 0.f, 0.f, 0.f}, ac1 = {0.f, 0.f, 0.f, 0.f};
            const int b0 = (wv_ * 32 + m16) * 512, b1 = b0 + 16 * 512;
            #pragma unroll
            for (int ks = 0; ks < 16; ++ks) {            // h0 new (agent)
                int k = ks * 32 + quad * 8;
                f16x8 w = *(const f16x8*)&WL[m16][k];
                f16x8 a0 = aload16(h0w + b0 + k);
                f16x8 a1 = aload16(h0w + b1 + k);
                ac0 = MFMA16(a0, w, ac0);
                ac1 = MFMA16(a1, w, ac1);
            }
            #pragma unroll
            for (int ks = 0; ks < 16; ++ks) {            // h1 prev (agent)
                int k = ks * 32 + quad * 8;
                f16x8 w = *(const f16x8*)&WL[m16][512 + k];
                f16x8 a0 = aload16(h1r + b0 + k);
                f16x8 a1 = aload16(h1r + b1 + k);
                ac0 = MFMA16(a0, w, ac0);
                ac1 = MFMA16(a1, w, ac1);
            }
            #pragma unroll
            for (int r = 0; r < 4; ++r) {
                gbuf[wv_][0][quad * 4 + r][m16] = ac0[r];
                gbuf[wv_][1][quad * 4 + r][m16] = ac1[r];
            }
            __syncthreads();
            const int v = bb >> 5, tau = (bb >> 4) & 1, row = bb & 15;
            float hv[2];
            #pragma unroll
            for (int j = 0; j < 2; ++j) {
                int c0l = (jb + j) * 4;
                float zi = gbuf[v][tau][row][c0l + 0] + bias[j][0];
                float zf = gbuf[v][tau][row][c0l + 1] + bias[j][1];
                float zg = gbuf[v][tau][row][c0l + 2] + bias[j][2];
                float zo = gbuf[v][tau][row][c0l + 3] + bias[j][3];
                float ig = 1.f / (1.f + expf(-zi));
                float fg = 1.f / (1.f + expf(-zf));
                float og = 1.f / (1.f + expf(-zo));
                float gg = tanhf(zg);
                float c = fg * ca[j] + ig * gg;
                ca[j] = c;
                hv[j] = og * tanhf(c);
            }
            union { f16 f[2]; unsigned u; } pk;
            pk.f[0] = (f16)hv[0]; pk.f[1] = (f16)hv[1];
            astore4(h1w + bb * 512 + nbase, pk.u);
            if (t == T - 1) {
                out_hT[BH + bb * 512 + nbase]     = hv[0];
                out_hT[BH + bb * 512 + nbase + 1] = hv[1];
                out_cT[BH + bb * 512 + nbase]     = ca[0];
                out_cT[BH + bb * 512 + nbase + 1] = ca[1];
            }
            arrive(bar2);
        }
        waitc(bar2, 128);

        // ============ phase C: attention + output (all 256 WGs) ============
        {
            if (tid < 128)
                ((u64*)h1s)[tid] = aload8((const u64*)(h1w + cb * 512) + tid);
            __syncthreads();

            // scores: wave handles 20 s; 64-lane dot over K=512
            for (int i = 0; i < 20; ++i) {
                int s = wv_ * 20 + i;
                const f16* cr = ctxWV + ((size_t)(cb * 80 + s)) * 1024 + lane * 8;
                f16x8 a = *(const f16x8*)cr;
                f16x8 h = *(const f16x8*)&h1s[lane * 8];
                float d = 0.f;
                #pragma unroll
                for (int j = 0; j < 8; ++j) d += (float)a[j] * (float)h[j];
                #pragma unroll
                for (int o = 32; o > 0; o >>= 1) d += __shfl_xor(d, o);
                if (lane == 0) scf[s] = d;
            }
            __syncthreads();
            if (wv_ == 0) {
                float e0 = scf[lane];
                float e1 = (lane < 16) ? scf[64 + lane] : -1e30f;
                float m = fmaxf(e0, e1);
                #pragma unroll
                for (int o = 32; o > 0; o >>= 1) m = fmaxf(m, __shfl_xor(m, o));
                float x0 = expf(e0 - m);
                float x1 = (lane < 16) ? expf(e1 - m) : 0.f;
                float su = x0 + x1;
                #pragma unroll
                for (int o = 32; o > 0; o >>= 1) su += __shfl_xor(su, o);
                float inv = 1.f / su;
                float p0 = x0 * inv;
                pp[lane] = p0;
                out_attn[((size_t)t * 128 + cb) * 80 + lane] = p0;
                if (lane < 16) {
                    float p1 = x1 * inv;
                    pp[64 + lane] = p1;
                    out_attn[((size_t)t * 128 + cb) * 80 + 64 + lane] = p1;
                }
            }
            __syncthreads();

            // out[n] = tanh( sum_s p*ctxV[s][n] + sum_k WoutR[n][k]*h1[k] )
            const int nloc = wv_ * 64 + lane;            // [0,256)
            const int n = nh * 256 + nloc;
            float acc = 0.f;
            {
                const f16* cv = ctxWV + (size_t)cb * 80 * 1024 + 512 + n;
                #pragma unroll 8
                for (int s = 0; s < 80; ++s) acc += pp[s] * (float)cv[(size_t)s * 1024];
            }
            float acc2 = 0.f;
            {
                const f16* wr = WoutRf + (size_t)n * 512;
                #pragma unroll 8
                for (int kk = 0; kk < 64; ++kk) {
                    f16x8 w = *(const f16x8*)(wr + kk * 8);
                    f16x8 h = *(const f16x8*)&h1s[kk * 8];
                    #pragma unroll
                    for (int j = 0; j < 8; ++j) acc2 += (float)w[j] * (float)h[j];
                }
            }
            float o = tanhf(acc + acc2);
            out_outputs[(size_t)t * BH + cb * 512 + n] = o;
            obuf[nloc] = (f16)o;
            __syncthreads();
            if (tid < 64)
                astore8(xprev + cb * 512 + nh * 256 + tid * 4, ((const u64*)obuf)[tid]);
        }
        arrive(bar3);
        waitc(bar3, 256);
    }
}

// ---------------------------------------------------------------------------
extern "C" void kernel_launch(void* const* d_in, const int* in_sizes, int n_in,
                              void* d_out, int out_size, void* d_ws, size_t ws_size,
                              hipStream_t stream)
{
    const int*   tokens  = (const int*)  d_in[0];
    const float* h0      = (const float*)d_in[1];
    const float* c0      = (const float*)d_in[2];
    const float* context = (const float*)d_in[3];
    const float* embtab  = (const float*)d_in[4];
    const float* Wih0    = (const float*)d_in[5];
    const float* Whh0    = (const float*)d_in[6];
    const float* bih0    = (const float*)d_in[7];
    const float* bhh0    = (const float*)d_in[8];
    const float* Wih1    = (const float*)d_in[9];
    const float* Whh1    = (const float*)d_in[10];
    const float* bih1    = (const float*)d_in[11];
    const float* bhh1    = (const float*)d_in[12];
    const float* Win     = (const float*)d_in[13];
    const float* Wout    = (const float*)d_in[14];

    float* outF        = (float*)d_out;
    float* out_outputs = outF;
    float* out_hT      = outF + (size_t)T * BH;
    float* out_cT      = out_hT + 2 * BH;
    float* out_attn    = out_cT + 2 * BH;

    char* w = (char*)d_ws;
    auto alloc = [&](size_t bytes) {
        char* p = w;
        w += (bytes + 255) & ~(size_t)255;
        return p;
    };
    f16*      WB0p   = (f16*)     alloc((size_t)2048 * 1536 * 2);
    f16*      WB1p   = (f16*)     alloc((size_t)2048 * 1024 * 2);
    f16*      WoutRf = (f16*)     alloc((size_t)512 * 512 * 2);
    f16*      WcatT  = (f16*)     alloc((size_t)1024 * 512 * 2);
    f16*      embf16 = (f16*)     alloc((size_t)T * B * 512 * 2);
    f16*      ctxWV  = (f16*)     alloc((size_t)B * S * 1024 * 2);
    float*    bsum0  = (float*)   alloc(2048 * 4);
    float*    bsum1  = (float*)   alloc(2048 * 4);
    f16*      h0buf  = (f16*)     alloc((size_t)2 * BH * 2);
    f16*      h1buf  = (f16*)     alloc((size_t)2 * BH * 2);
    f16*      xprev  = (f16*)     alloc((size_t)BH * 2);
    unsigned* bars   = (unsigned*)alloc(256 * 4);

    prep_all<<<1024, 256, 0, stream>>>(Wih0, Whh0, Wih1, Whh1, Wout, Win,
                                       bih0, bhh0, bih1, bhh1, h0, c0,
                                       WB0p, WB1p, WoutRf, WcatT, bsum0, bsum1,
                                       h0buf, h1buf, xprev, bars);
    prep_emb<<<2048, 256, 0, stream>>>(tokens, embtab, embf16);
    gemm_ctx<<<dim3(32, 320), 256, 0, stream>>>(context, WcatT, ctxWV);

    decoder_persist<<<NWG, 256, 0, stream>>>(
        embf16, WB0p, WB1p, WoutRf, ctxWV, bsum0, bsum1, c0,
        h0buf, h1buf, xprev, bars,
        out_outputs, out_attn, out_hT, out_cT);
}

// Round 4
// 5284.182 us; speedup vs baseline: 1.1783x; 1.1200x over previous
//
#include <hip/hip_runtime.h>
#include <hip/hip_fp16.h>
#include <cmath>

typedef _Float16 f16;
typedef _Float16 f16x8 __attribute__((ext_vector_type(8)));
typedef float f32x4 __attribute__((ext_vector_type(4)));
typedef unsigned long long u64;

constexpr int B = 128, T = 64, S = 80, H = 512;
constexpr int BH = B * H;      // 65536
constexpr int NWG = 512;

#define LB256 __launch_bounds__(256)
#define MFMA16(a, b, c) __builtin_amdgcn_mfma_f32_16x16x32_f16(a, b, c, 0, 0, 0)

// ---- agent-scope write-through / uncached accessors (small data only) ------
__device__ __forceinline__ void astore4(void* p, unsigned v) {
    __hip_atomic_store((unsigned*)p, v, __ATOMIC_RELAXED, __HIP_MEMORY_SCOPE_AGENT);
}
__device__ __forceinline__ void astoref(float* p, float v) {
    __hip_atomic_store(p, v, __ATOMIC_RELAXED, __HIP_MEMORY_SCOPE_AGENT);
}
__device__ __forceinline__ void astore8(void* p, u64 v) {
    __hip_atomic_store((u64*)p, v, __ATOMIC_RELAXED, __HIP_MEMORY_SCOPE_AGENT);
}
__device__ __forceinline__ u64 aload8(const void* p) {
    return __hip_atomic_load((const u64*)p, __ATOMIC_RELAXED, __HIP_MEMORY_SCOPE_AGENT);
}
__device__ __forceinline__ unsigned aload4(const void* p) {
    return __hip_atomic_load((const unsigned*)p, __ATOMIC_RELAXED, __HIP_MEMORY_SCOPE_AGENT);
}

// ---- relaxed grid barrier: no cache maintenance anywhere -------------------
// __syncthreads drains vmcnt (write-through stores reach MALL), then one
// relaxed agent RMW. Waiters poll with relaxed agent loads (uncached).
__device__ __forceinline__ void arrive(unsigned* c) {
    __syncthreads();
    if (threadIdx.x == 0)
        __hip_atomic_fetch_add(c, 1u, __ATOMIC_RELAXED, __HIP_MEMORY_SCOPE_AGENT);
}
__device__ __forceinline__ void waitc(unsigned* c, unsigned tgt) {
    if (threadIdx.x == 0) {
        while (__hip_atomic_load(c, __ATOMIC_RELAXED, __HIP_MEMORY_SCOPE_AGENT) < tgt)
            __builtin_amdgcn_s_sleep(1);
    }
    __syncthreads();
    asm volatile("" ::: "memory");   // block load hoisting above the spin
}

// ---------------------------------------------------------------------------
__global__ LB256 void prep_all(
    const float* __restrict__ Wih0, const float* __restrict__ Whh0,
    const float* __restrict__ Wih1, const float* __restrict__ Whh1,
    const float* __restrict__ Wout, const float* __restrict__ Win,
    const float* __restrict__ bih0, const float* __restrict__ bhh0,
    const float* __restrict__ bih1, const float* __restrict__ bhh1,
    const float* __restrict__ h0,
    f16* __restrict__ WB0a, f16* __restrict__ WB0x, f16* __restrict__ WB1p,
    f16* __restrict__ WoutRf, f16* __restrict__ WcatT,
    float* __restrict__ bsum0, float* __restrict__ bsum1,
    f16* __restrict__ h0q, f16* __restrict__ h1q, f16* __restrict__ xq,
    unsigned* __restrict__ bars)
{
    int stride = gridDim.x * blockDim.x;
    int idx = blockIdx.x * blockDim.x + threadIdx.x;
    // row' = h*4+g gate-interleaved.  WB0a[row'][k] = Wih0[g*512+h][k]  (emb part)
    for (int i = idx; i < 2048 * 512; i += stride) {
        int rp = i >> 9, k = i & 511;
        int h = rp >> 2, g = rp & 3, src = g * 512 + h;
        WB0a[i] = (f16)Wih0[src * 1024 + k];
    }
    // WB0x[row'][k]: k<512 -> Wih0[src][512+k] (xprev), else Whh0[src][k-512]
    for (int i = idx; i < 2048 * 1024; i += stride) {
        int rp = i >> 10, k = i & 1023;
        int h = rp >> 2, g = rp & 3, src = g * 512 + h;
        float v = (k < 512) ? Wih0[src * 1024 + 512 + k] : Whh0[src * 512 + (k - 512)];
        WB0x[i] = (f16)v;
    }
    // WB1p[row'][k]: k<512 Wih1 else Whh1
    for (int i = idx; i < 2048 * 1024; i += stride) {
        int rp = i >> 10, k = i & 1023;
        int h = rp >> 2, g = rp & 3, src = g * 512 + h;
        float v = (k < 512) ? Wih1[src * 512 + k] : Whh1[src * 512 + (k - 512)];
        WB1p[i] = (f16)v;
    }
    // WoutRf[n][k] = W_out[n][512+k]
    for (int i = idx; i < 512 * 512; i += stride) {
        int n = i >> 9, k = i & 511;
        WoutRf[i] = (f16)Wout[n * 1024 + 512 + k];
    }
    // WcatT rows 0-511: Win^T; rows 512-1023: W_out left half
    for (int i = idx; i < 1024 * 512; i += stride) {
        int r = i >> 9, k = i & 511;
        float v = (r < 512) ? Win[k * 512 + r] : Wout[(r - 512) * 1024 + k];
        WcatT[i] = (f16)v;
    }
    for (int i = idx; i < 2048; i += stride) {
        bsum0[i] = bih0[i] + bhh0[i];
        bsum1[i] = bih1[i] + bhh1[i];
    }
    for (int i = idx; i < BH; i += stride) {
        h0q[i] = (f16)h0[i];        // ring slot 0
        h1q[i] = (f16)h0[BH + i];
        xq[i] = (f16)0.f;
    }
    for (int i = idx; i < 512; i += stride) bars[i] = 0u;
}

__global__ LB256 void prep_emb(const int* __restrict__ tokens,
                               const float* __restrict__ embtab,
                               f16* __restrict__ embf16)
{
    int stride = gridDim.x * blockDim.x;
    for (int i = blockIdx.x * blockDim.x + threadIdx.x; i < T * B * 512; i += stride) {
        int e = i & 511;
        int tb = i >> 9;
        int tok = tokens[tb];
        embf16[i] = (f16)embtab[(size_t)tok * 512 + e];
    }
}

// ctxWV[m][j] = sum_k ctx_flat[m][k] * WcatT[j][k]
__global__ LB256 void gemm_ctx(const float* __restrict__ A32,
                               const f16* __restrict__ Wf,
                               f16* __restrict__ Cf)
{
    const int lane = threadIdx.x & 63;
    const int wave = threadIdx.x >> 6;
    const int quad = lane >> 4;
    const int wb = wave >> 1, wn = wave & 1;
    const int m = blockIdx.y * 32 + wb * 16 + (lane & 15);
    const int n = blockIdx.x * 32 + wn * 16 + (lane & 15);

    f32x4 acc = {0.f, 0.f, 0.f, 0.f};
    const float* ar = A32 + (size_t)m * 512;
    const f16* wr = Wf + (size_t)n * 512;
    #pragma unroll 4
    for (int i = 0; i < 16; ++i) {
        int k = i * 32 + quad * 8;
        float4 u0 = *(const float4*)(ar + k);
        float4 u1 = *(const float4*)(ar + k + 4);
        f16x8 av = { (f16)u0.x, (f16)u0.y, (f16)u0.z, (f16)u0.w,
                     (f16)u1.x, (f16)u1.y, (f16)u1.z, (f16)u1.w };
        f16x8 wv = *(const f16x8*)(wr + k);
        acc = MFMA16(av, wv, acc);
    }
    const int col = blockIdx.x * 32 + wn * 16 + (lane & 15);
    #pragma unroll
    for (int r = 0; r < 4; ++r) {
        int row = blockIdx.y * 32 + wb * 16 + quad * 4 + r;
        Cf[(size_t)row * 1024 + col] = (f16)acc[r];
    }
}

// ---------------------------------------------------------------------------
// persistent decoder: 512 WGs x 256 thr (2 WGs/CU), 4 relaxed barriers/step.
// Cross-WG activations: write-through stores into per-step rotated buffers,
// read back with normal cached vector loads (fresh address => no staleness).
__global__ __launch_bounds__(256, 2) void decoder_persist(
    const f16* __restrict__ embf16,   // [T][B][512]
    const f16* __restrict__ WB0a,     // [2048][512]  emb-part weights (L2)
    const f16* __restrict__ WB0x,     // [2048][1024] xprev|h0 weights -> LDS
    const f16* __restrict__ WB1p,     // [2048][1024] lstm1 weights -> LDS
    const f16* __restrict__ WoutRf,   // [512][512]   (L2)
    const f16* __restrict__ ctxWV,    // [B*S][1024]
    const float* __restrict__ bsum0, const float* __restrict__ bsum1,
    const float* __restrict__ c0in,   // [2][B][512]
    f16* __restrict__ h0q,            // [T+1][B][512] ring
    f16* __restrict__ h1q,            // [T+1][B][512] ring
    f16* __restrict__ xq,             // [T+1][B][512] ring
    float* __restrict__ scb,          // [B][80]   (uncached path)
    f16* __restrict__ out2b,          // [B][512]  (uncached path)
    unsigned* __restrict__ bars,
    float* __restrict__ out_outputs, float* __restrict__ out_attn,
    float* __restrict__ out_hT, float* __restrict__ out_cT)
{
    const int wg = blockIdx.x, tid = threadIdx.x;
    const int lane = tid & 63, wv_ = tid >> 6, quad = lane >> 4, m16 = lane & 15;
    const int mslice = wg >> 7;          // 0..3   (32 b rows)
    const int nslice = wg & 127;         // 0..127 (16 gate rows = 4 h dims)
    const int b0 = mslice * 32;
    const int rowbase = nslice * 16;

    __shared__ f16 WLA[16 * 1024];       // xprev|h0 weights, XOR-swizzled
    __shared__ f16 WLB[16 * 1024];       // lstm1 weights
    __shared__ float gbuf[4][32][16];
    __shared__ float scf[80], pp[80];
    __shared__ unsigned o2buf[128];
    __shared__ f16 obuf[256];

    // ---- one-time: weights -> LDS (granule g stored at g ^ (row&7)) ----
    for (int i = tid; i < 2048; i += 256) {
        int r = i >> 7, g = i & 127, gp = g ^ (r & 7);
        *(f16x8*)(WLA + (r * 128 + gp) * 8) =
            *(const f16x8*)(WB0x + ((size_t)(rowbase + r)) * 1024 + g * 8);
        *(f16x8*)(WLB + (r * 128 + gp) * 8) =
            *(const f16x8*)(WB1p + ((size_t)(rowbase + r)) * 1024 + g * 8);
    }
    // cell state registers: thread tid<64 owns (b = tid&31, h = nslice*4 + jp+{0,1})
    const int cb_ = b0 + (tid & 31);
    const int jp = (tid >> 5) * 2;       // 0 or 2 (tid<64)
    const int ch = nslice * 4 + jp;
    float c0r[2], c1r[2], bi0[2][4], bi1[2][4];
    if (tid < 64) {
        #pragma unroll
        for (int j = 0; j < 2; ++j) {
            c0r[j] = c0in[cb_ * 512 + ch + j];
            c1r[j] = c0in[BH + cb_ * 512 + ch + j];
            #pragma unroll
            for (int g = 0; g < 4; ++g) {
                bi0[j][g] = bsum0[g * 512 + ch + j];
                bi1[j][g] = bsum1[g * 512 + ch + j];
            }
        }
    }
    // C1 scores role
    const int b_s = wg >> 2;
    const int soff = (wg & 3) * 20;
    // C1 out2 role (wg < 128)
    const int m2 = wg >> 5, n2 = wg & 31;
    // C2 role (wg < 256)
    const int b2 = wg >> 1, nh = wg & 1;
    __syncthreads();

    for (int t = 0; t < T; ++t) {
        const f16* EMBt = embf16 + (size_t)t * BH;
        const f16* XPt  = xq  + (size_t)t * BH;
        const f16* H0t  = h0q + (size_t)t * BH;
        const f16* H1t  = h1q + (size_t)t * BH;
        f16* H0n = h0q + (size_t)(t + 1) * BH;
        f16* H1n = h1q + (size_t)(t + 1) * BH;
        f16* XPn = xq  + (size_t)(t + 1) * BH;
        unsigned* barA  = &bars[t * 4];
        unsigned* barB  = barA + 1;
        unsigned* barC1 = barA + 2;
        unsigned* barC2 = barA + 3;

        // ================= phase A: lstm0 gates, K=1536 k-split over waves ==
        {
            f32x4 ac0 = {0.f, 0.f, 0.f, 0.f}, ac1 = {0.f, 0.f, 0.f, 0.f};
            const int a0r = (b0 + m16) * 512 + quad * 8;
            const int a1r = (b0 + 16 + m16) * 512 + quad * 8;
            const f16* wga = WB0a + (size_t)(rowbase + m16) * 512 + quad * 8;
            const int gq = quad;
            if (wv_ == 0) {                      // emb k 0..384
                #pragma unroll
                for (int ks = 0; ks < 12; ++ks) {
                    int k = ks * 32;
                    f16x8 w = *(const f16x8*)(wga + k);
                    ac0 = MFMA16(*(const f16x8*)(EMBt + a0r + k), w, ac0);
                    ac1 = MFMA16(*(const f16x8*)(EMBt + a1r + k), w, ac1);
                }
            } else if (wv_ == 1) {               // emb 384..512 + xprev 0..256
                #pragma unroll
                for (int ks = 0; ks < 4; ++ks) {
                    int k = 384 + ks * 32;
                    f16x8 w = *(const f16x8*)(wga + k);
                    ac0 = MFMA16(*(const f16x8*)(EMBt + a0r + k), w, ac0);
                    ac1 = MFMA16(*(const f16x8*)(EMBt + a1r + k), w, ac1);
                }
                #pragma unroll
                for (int ks = 0; ks < 8; ++ks) {
                    int k = ks * 32;
                    int gr = (k >> 3) + gq, gp = gr ^ (m16 & 7);
                    f16x8 w = *(const f16x8*)(WLA + (m16 * 128 + gp) * 8);
                    ac0 = MFMA16(*(const f16x8*)(XPt + a0r + k), w, ac0);
                    ac1 = MFMA16(*(const f16x8*)(XPt + a1r + k), w, ac1);
                }
            } else if (wv_ == 2) {               // xprev 256..512 + h0r 0..128
                #pragma unroll
                for (int ks = 0; ks < 8; ++ks) {
                    int k = 256 + ks * 32;
                    int gr = (k >> 3) + gq, gp = gr ^ (m16 & 7);
                    f16x8 w = *(const f16x8*)(WLA + (m16 * 128 + gp) * 8);
                    ac0 = MFMA16(*(const f16x8*)(XPt + a0r + k), w, ac0);
                    ac1 = MFMA16(*(const f16x8*)(XPt + a1r + k), w, ac1);
                }
                #pragma unroll
                for (int ks = 0; ks < 4; ++ks) {
                    int k = ks * 32;
                    int gr = 64 + (k >> 3) + gq, gp = gr ^ (m16 & 7);
                    f16x8 w = *(const f16x8*)(WLA + (m16 * 128 + gp) * 8);
                    ac0 = MFMA16(*(const f16x8*)(H0t + a0r + k), w, ac0);
                    ac1 = MFMA16(*(const f16x8*)(H0t + a1r + k), w, ac1);
                }
            } else {                             // h0r 128..512
                #pragma unroll
                for (int ks = 0; ks < 12; ++ks) {
                    int k = 128 + ks * 32;
                    int gr = 64 + (k >> 3) + gq, gp = gr ^ (m16 & 7);
                    f16x8 w = *(const f16x8*)(WLA + (m16 * 128 + gp) * 8);
                    ac0 = MFMA16(*(const f16x8*)(H0t + a0r + k), w, ac0);
                    ac1 = MFMA16(*(const f16x8*)(H0t + a1r + k), w, ac1);
                }
            }
            #pragma unroll
            for (int r = 0; r < 4; ++r) {
                gbuf[wv_][quad * 4 + r][m16] = ac0[r];
                gbuf[wv_][16 + quad * 4 + r][m16] = ac1[r];
            }
            __syncthreads();
            if (tid < 64) {
                const int bl = tid & 31;
                float hv[2];
                #pragma unroll
                for (int j = 0; j < 2; ++j) {
                    int nl = (jp + j) * 4;
                    float z[4];
                    #pragma unroll
                    for (int g = 0; g < 4; ++g)
                        z[g] = gbuf[0][bl][nl + g] + gbuf[1][bl][nl + g] +
                               gbuf[2][bl][nl + g] + gbuf[3][bl][nl + g] + bi0[j][g];
                    float ig = 1.f / (1.f + expf(-z[0]));
                    float fg = 1.f / (1.f + expf(-z[1]));
                    float gg = tanhf(z[2]);
                    float og = 1.f / (1.f + expf(-z[3]));
                    float c = fg * c0r[j] + ig * gg;
                    c0r[j] = c;
                    hv[j] = og * tanhf(c);
                }
                union { f16 f[2]; unsigned u; } pk;
                pk.f[0] = (f16)hv[0]; pk.f[1] = (f16)hv[1];
                astore4(H0n + cb_ * 512 + ch, pk.u);
                if (t == T - 1) {
                    out_hT[cb_ * 512 + ch] = hv[0];
                    out_hT[cb_ * 512 + ch + 1] = hv[1];
                    out_cT[cb_ * 512 + ch] = c0r[0];
                    out_cT[cb_ * 512 + ch + 1] = c0r[1];
                }
            }
        }
        arrive(barA);
        waitc(barA, NWG);

        // ================= phase B: lstm1 gates, K=1024 =================
        {
            f32x4 ac0 = {0.f, 0.f, 0.f, 0.f}, ac1 = {0.f, 0.f, 0.f, 0.f};
            const int a0r = (b0 + m16) * 512 + quad * 8;
            const int a1r = (b0 + 16 + m16) * 512 + quad * 8;
            const f16* Asrc = (wv_ < 2) ? H0n : H1t;
            const int k0 = (wv_ & 1) * 256;
            const int gbase = ((wv_ < 2) ? 0 : 64) + (k0 >> 3);
            #pragma unroll
            for (int ks = 0; ks < 8; ++ks) {
                int k = k0 + ks * 32;
                int gr = gbase + ks * 4 + quad, gp = gr ^ (m16 & 7);
                f16x8 w = *(const f16x8*)(WLB + (m16 * 128 + gp) * 8);
                ac0 = MFMA16(*(const f16x8*)(Asrc + a0r + k), w, ac0);
                ac1 = MFMA16(*(const f16x8*)(Asrc + a1r + k), w, ac1);
            }
            #pragma unroll
            for (int r = 0; r < 4; ++r) {
                gbuf[wv_][quad * 4 + r][m16] = ac0[r];
                gbuf[wv_][16 + quad * 4 + r][m16] = ac1[r];
            }
            __syncthreads();
            if (tid < 64) {
                const int bl = tid & 31;
                float hv[2];
                #pragma unroll
                for (int j = 0; j < 2; ++j) {
                    int nl = (jp + j) * 4;
                    float z[4];
                    #pragma unroll
                    for (int g = 0; g < 4; ++g)
                        z[g] = gbuf[0][bl][nl + g] + gbuf[1][bl][nl + g] +
                               gbuf[2][bl][nl + g] + gbuf[3][bl][nl + g] + bi1[j][g];
                    float ig = 1.f / (1.f + expf(-z[0]));
                    float fg = 1.f / (1.f + expf(-z[1]));
                    float gg = tanhf(z[2]);
                    float og = 1.f / (1.f + expf(-z[3]));
                    float c = fg * c1r[j] + ig * gg;
                    c1r[j] = c;
                    hv[j] = og * tanhf(c);
                }
                union { f16 f[2]; unsigned u; } pk;
                pk.f[0] = (f16)hv[0]; pk.f[1] = (f16)hv[1];
                astore4(H1n + cb_ * 512 + ch, pk.u);
                if (t == T - 1) {
                    out_hT[BH + cb_ * 512 + ch] = hv[0];
                    out_hT[BH + cb_ * 512 + ch + 1] = hv[1];
                    out_cT[BH + cb_ * 512 + ch] = c1r[0];
                    out_cT[BH + cb_ * 512 + ch + 1] = c1r[1];
                }
            }
        }
        arrive(barB);
        waitc(barB, NWG);

        // ================= phase C1: scores (all) + out2 GEMM (wg<128) =====
        {
            // scores: b_s, s = soff + wv_*5 + i ; 64-lane dot over K=512
            const f16* hrow = H1n + b_s * 512;
            f16x8 hfrag = *(const f16x8*)(hrow + lane * 8);
            #pragma unroll
            for (int i = 0; i < 5; ++i) {
                int s = soff + wv_ * 5 + i;
                const f16* cr = ctxWV + ((size_t)(b_s * 80 + s)) * 1024 + lane * 8;
                f16x8 a = *(const f16x8*)cr;
                float d = 0.f;
                #pragma unroll
                for (int j = 0; j < 8; ++j) d += (float)a[j] * (float)hfrag[j];
                #pragma unroll
                for (int o = 32; o > 0; o >>= 1) d += __shfl_xor(d, o);
                if (lane == 0) astoref(&scb[b_s * 80 + s], d);
            }
            if (wg < 128) {
                // out2[m2*32.., n2*16..] = h1 . WoutR^T, K=512 split over waves
                f32x4 ac0 = {0.f, 0.f, 0.f, 0.f}, ac1 = {0.f, 0.f, 0.f, 0.f};
                const int bb0 = m2 * 32;
                const int a0r = (bb0 + m16) * 512 + quad * 8;
                const int a1r = (bb0 + 16 + m16) * 512 + quad * 8;
                const f16* wr = WoutRf + (size_t)(n2 * 16 + m16) * 512 + quad * 8;
                const int k0 = wv_ * 128;
                #pragma unroll
                for (int ks = 0; ks < 4; ++ks) {
                    int k = k0 + ks * 32;
                    f16x8 w = *(const f16x8*)(wr + k);
                    ac0 = MFMA16(*(const f16x8*)(H1n + a0r + k), w, ac0);
                    ac1 = MFMA16(*(const f16x8*)(H1n + a1r + k), w, ac1);
                }
                __syncthreads();
                #pragma unroll
                for (int r = 0; r < 4; ++r) {
                    gbuf[wv_][quad * 4 + r][m16] = ac0[r];
                    gbuf[wv_][16 + quad * 4 + r][m16] = ac1[r];
                }
                __syncthreads();
                // 256 threads: (b = tid>>3, npair = (tid&7)*2)
                const int bl = tid >> 3, np = (tid & 7) * 2;
                float v0 = gbuf[0][bl][np] + gbuf[1][bl][np] + gbuf[2][bl][np] + gbuf[3][bl][np];
                float v1 = gbuf[0][bl][np+1] + gbuf[1][bl][np+1] + gbuf[2][bl][np+1] + gbuf[3][bl][np+1];
                union { f16 f[2]; unsigned u; } pk;
                pk.f[0] = (f16)v0; pk.f[1] = (f16)v1;
                astore4(out2b + (bb0 + bl) * 512 + n2 * 16 + np, pk.u);
            }
        }
        arrive(barC1);

        // ================= phase C2: softmax + ctxV reduce + out (wg<256) ==
        if (wg < 256) {
            waitc(barC1, NWG);
            if (wv_ == 0 && lane < 40) {
                union { u64 u; float f[2]; } v;
                v.u = aload8(&scb[b2 * 80 + lane * 2]);
                scf[lane * 2] = v.f[0];
                scf[lane * 2 + 1] = v.f[1];
            }
            if (tid < 128)
                o2buf[tid] = aload4((const unsigned*)(out2b + b2 * 512 + nh * 256) + tid);
            __syncthreads();
            if (wv_ == 0) {
                float e0 = scf[lane];
                float e1 = (lane < 16) ? scf[64 + lane] : -1e30f;
                float m = fmaxf(e0, e1);
                #pragma unroll
                for (int o = 32; o > 0; o >>= 1) m = fmaxf(m, __shfl_xor(m, o));
                float x0 = expf(e0 - m);
                float x1 = (lane < 16) ? expf(e1 - m) : 0.f;
                float su = x0 + x1;
                #pragma unroll
                for (int o = 32; o > 0; o >>= 1) su += __shfl_xor(su, o);
                float inv = 1.f / su;
                float p0 = x0 * inv;
                pp[lane] = p0;
                if (nh == 0) out_attn[((size_t)t * 128 + b2) * 80 + lane] = p0;
                if (lane < 16) {
                    float p1 = x1 * inv;
                    pp[64 + lane] = p1;
                    if (nh == 0) out_attn[((size_t)t * 128 + b2) * 80 + 64 + lane] = p1;
                }
            }
            __syncthreads();
            const int n = nh * 256 + tid;
            float acc = 0.f;
            const f16* cv = ctxWV + (size_t)b2 * 80 * 1024 + 512 + n;
            #pragma unroll 8
            for (int s = 0; s < 80; ++s) acc += pp[s] * (float)cv[(size_t)s * 1024];
            float o2 = (float)((const f16*)o2buf)[tid];
            float o = tanhf(acc + o2);
            out_outputs[(size_t)t * BH + b2 * 512 + n] = o;
            obuf[tid] = (f16)o;
            __syncthreads();
            if (tid < 64)
                astore8(XPn + b2 * 512 + nh * 256 + tid * 4, ((const u64*)obuf)[tid]);
        }
        arrive(barC2);
        waitc(barC2, NWG);
    }
}

// ---------------------------------------------------------------------------
extern "C" void kernel_launch(void* const* d_in, const int* in_sizes, int n_in,
                              void* d_out, int out_size, void* d_ws, size_t ws_size,
                              hipStream_t stream)
{
    const int*   tokens  = (const int*)  d_in[0];
    const float* h0      = (const float*)d_in[1];
    const float* c0      = (const float*)d_in[2];
    const float* context = (const float*)d_in[3];
    const float* embtab  = (const float*)d_in[4];
    const float* Wih0    = (const float*)d_in[5];
    const float* Whh0    = (const float*)d_in[6];
    const float* bih0    = (const float*)d_in[7];
    const float* bhh0    = (const float*)d_in[8];
    const float* Wih1    = (const float*)d_in[9];
    const float* Whh1    = (const float*)d_in[10];
    const float* bih1    = (const float*)d_in[11];
    const float* bhh1    = (const float*)d_in[12];
    const float* Win     = (const float*)d_in[13];
    const float* Wout    = (const float*)d_in[14];

    float* outF        = (float*)d_out;
    float* out_outputs = outF;
    float* out_hT      = outF + (size_t)T * BH;
    float* out_cT      = out_hT + 2 * BH;
    float* out_attn    = out_cT + 2 * BH;

    char* w = (char*)d_ws;
    auto alloc = [&](size_t bytes) {
        char* p = w;
        w += (bytes + 255) & ~(size_t)255;
        return p;
    };
    f16*      WB0a   = (f16*)     alloc((size_t)2048 * 512 * 2);
    f16*      WB0x   = (f16*)     alloc((size_t)2048 * 1024 * 2);
    f16*      WB1p   = (f16*)     alloc((size_t)2048 * 1024 * 2);
    f16*      WoutRf = (f16*)     alloc((size_t)512 * 512 * 2);
    f16*      WcatT  = (f16*)     alloc((size_t)1024 * 512 * 2);
    f16*      embf16 = (f16*)     alloc((size_t)T * B * 512 * 2);
    f16*      ctxWV  = (f16*)     alloc((size_t)B * S * 1024 * 2);
    float*    bsum0  = (float*)   alloc(2048 * 4);
    float*    bsum1  = (float*)   alloc(2048 * 4);
    f16*      h0q    = (f16*)     alloc((size_t)(T + 1) * BH * 2);
    f16*      h1q    = (f16*)     alloc((size_t)(T + 1) * BH * 2);
    f16*      xq     = (f16*)     alloc((size_t)(T + 1) * BH * 2);
    float*    scb    = (float*)   alloc((size_t)B * 80 * 4);
    f16*      out2b  = (f16*)     alloc((size_t)B * 512 * 2);
    unsigned* bars   = (unsigned*)alloc(512 * 4);

    prep_all<<<1024, 256, 0, stream>>>(Wih0, Whh0, Wih1, Whh1, Wout, Win,
                                       bih0, bhh0, bih1, bhh1, h0,
                                       WB0a, WB0x, WB1p, WoutRf, WcatT,
                                       bsum0, bsum1, h0q, h1q, xq, bars);
    prep_emb<<<2048, 256, 0, stream>>>(tokens, embtab, embf16);
    gemm_ctx<<<dim3(32, 320), 256, 0, stream>>>(context, WcatT, ctxWV);

    decoder_persist<<<NWG, 256, 0, stream>>>(
        embf16, WB0a, WB0x, WB1p, WoutRf, ctxWV, bsum0, bsum1, c0,
        h0q, h1q, xq, scb, out2b, bars,
        out_outputs, out_attn, out_hT, out_cT);
}

// Round 5
// 2078.298 us; speedup vs baseline: 2.9959x; 2.5426x over previous
//
#include <hip/hip_runtime.h>
#include <hip/hip_fp16.h>
#include <cmath>

typedef _Float16 f16;
typedef _Float16 f16x8 __attribute__((ext_vector_type(8)));
typedef float f32x4 __attribute__((ext_vector_type(4)));
typedef unsigned long long u64;

constexpr int B = 128, T = 64, S = 80, H = 512;
constexpr int BH = B * H;      // 65536
constexpr int NWG = 512;

#define LB256 __launch_bounds__(256)
#define MFMA16(a, b, c) __builtin_amdgcn_mfma_f32_16x16x32_f16(a, b, c, 0, 0, 0)

// ---- agent-scope write-through / uncached accessors ------------------------
__device__ __forceinline__ void astore4(void* p, unsigned v) {
    __hip_atomic_store((unsigned*)p, v, __ATOMIC_RELAXED, __HIP_MEMORY_SCOPE_AGENT);
}
__device__ __forceinline__ void astoref(float* p, float v) {
    __hip_atomic_store(p, v, __ATOMIC_RELAXED, __HIP_MEMORY_SCOPE_AGENT);
}
__device__ __forceinline__ void astore8(void* p, u64 v) {
    __hip_atomic_store((u64*)p, v, __ATOMIC_RELAXED, __HIP_MEMORY_SCOPE_AGENT);
}
__device__ __forceinline__ u64 aload8(const void* p) {
    return __hip_atomic_load((const u64*)p, __ATOMIC_RELAXED, __HIP_MEMORY_SCOPE_AGENT);
}
__device__ __forceinline__ unsigned aload4(const void* p) {
    return __hip_atomic_load((const unsigned*)p, __ATOMIC_RELAXED, __HIP_MEMORY_SCOPE_AGENT);
}

// ---- distributed epoch barrier: no same-line RMW, no cache maintenance ----
// arrival: write-through store to own padded slot (parallel across lines).
// collector (wg NWG-1): 256 threads poll 2 slots each, then broadcast epoch
// into 16 replicated go-lines. pollers spin on their replica (32/line).
// __syncthreads before arrival drains each wave's vmcnt, so all phase
// stores are at the MALL before the slot store is issued.
__device__ __forceinline__ void dbar(unsigned* slots, unsigned* go,
                                     unsigned e, int wg) {
    __syncthreads();
    if (threadIdx.x == 0) astore4(&slots[wg * 4], e);
    if (wg == NWG - 1) {
        const int i0 = threadIdx.x * 2;
        while (aload4(&slots[i0 * 4]) < e) __builtin_amdgcn_s_sleep(1);
        while (aload4(&slots[(i0 + 1) * 4]) < e) __builtin_amdgcn_s_sleep(1);
        __syncthreads();
        if (threadIdx.x < 16) astore4(&go[threadIdx.x * 16], e);
    }
    if (threadIdx.x == 0) {
        while (aload4(&go[(wg & 15) * 16]) < e) __builtin_amdgcn_s_sleep(1);
    }
    __syncthreads();
    asm volatile("" ::: "memory");   // block load hoisting above the spin
}

// ---------------------------------------------------------------------------
__global__ LB256 void prep_all(
    const float* __restrict__ Wih0, const float* __restrict__ Whh0,
    const float* __restrict__ Wih1, const float* __restrict__ Whh1,
    const float* __restrict__ Wout, const float* __restrict__ Win,
    const float* __restrict__ bih0, const float* __restrict__ bhh0,
    const float* __restrict__ bih1, const float* __restrict__ bhh1,
    const float* __restrict__ h0,
    f16* __restrict__ WB0a, f16* __restrict__ WB0x, f16* __restrict__ WB1p,
    f16* __restrict__ WoutRf, f16* __restrict__ WcatT,
    float* __restrict__ bsum0, float* __restrict__ bsum1,
    f16* __restrict__ h0q, f16* __restrict__ h1q, f16* __restrict__ xq,
    unsigned* __restrict__ slots, unsigned* __restrict__ go)
{
    int stride = gridDim.x * blockDim.x;
    int idx = blockIdx.x * blockDim.x + threadIdx.x;
    // row' = h*4+g gate-interleaved.  WB0a[row'][k] = Wih0[g*512+h][k]  (emb part)
    for (int i = idx; i < 2048 * 512; i += stride) {
        int rp = i >> 9, k = i & 511;
        int h = rp >> 2, g = rp & 3, src = g * 512 + h;
        WB0a[i] = (f16)Wih0[src * 1024 + k];
    }
    // WB0x[row'][k]: k<512 -> Wih0[src][512+k] (xprev), else Whh0[src][k-512]
    for (int i = idx; i < 2048 * 1024; i += stride) {
        int rp = i >> 10, k = i & 1023;
        int h = rp >> 2, g = rp & 3, src = g * 512 + h;
        float v = (k < 512) ? Wih0[src * 1024 + 512 + k] : Whh0[src * 512 + (k - 512)];
        WB0x[i] = (f16)v;
    }
    // WB1p[row'][k]: k<512 Wih1 else Whh1
    for (int i = idx; i < 2048 * 1024; i += stride) {
        int rp = i >> 10, k = i & 1023;
        int h = rp >> 2, g = rp & 3, src = g * 512 + h;
        float v = (k < 512) ? Wih1[src * 512 + k] : Whh1[src * 512 + (k - 512)];
        WB1p[i] = (f16)v;
    }
    // WoutRf[n][k] = W_out[n][512+k]
    for (int i = idx; i < 512 * 512; i += stride) {
        int n = i >> 9, k = i & 511;
        WoutRf[i] = (f16)Wout[n * 1024 + 512 + k];
    }
    // WcatT rows 0-511: Win^T; rows 512-1023: W_out left half
    for (int i = idx; i < 1024 * 512; i += stride) {
        int r = i >> 9, k = i & 511;
        float v = (r < 512) ? Win[k * 512 + r] : Wout[(r - 512) * 1024 + k];
        WcatT[i] = (f16)v;
    }
    for (int i = idx; i < 2048; i += stride) {
        bsum0[i] = bih0[i] + bhh0[i];
        bsum1[i] = bih1[i] + bhh1[i];
    }
    for (int i = idx; i < BH; i += stride) {
        h0q[i] = (f16)h0[i];        // ring slot 0
        h1q[i] = (f16)h0[BH + i];
        xq[i] = (f16)0.f;
    }
    for (int i = idx; i < 2048; i += stride) slots[i] = 0u;
    for (int i = idx; i < 256; i += stride) go[i] = 0u;
}

__global__ LB256 void prep_emb(const int* __restrict__ tokens,
                               const float* __restrict__ embtab,
                               f16* __restrict__ embf16)
{
    int stride = gridDim.x * blockDim.x;
    for (int i = blockIdx.x * blockDim.x + threadIdx.x; i < T * B * 512; i += stride) {
        int e = i & 511;
        int tb = i >> 9;
        int tok = tokens[tb];
        embf16[i] = (f16)embtab[(size_t)tok * 512 + e];
    }
}

// ctxWV[m][j] = sum_k ctx_flat[m][k] * WcatT[j][k]
__global__ LB256 void gemm_ctx(const float* __restrict__ A32,
                               const f16* __restrict__ Wf,
                               f16* __restrict__ Cf)
{
    const int lane = threadIdx.x & 63;
    const int wave = threadIdx.x >> 6;
    const int quad = lane >> 4;
    const int wb = wave >> 1, wn = wave & 1;
    const int m = blockIdx.y * 32 + wb * 16 + (lane & 15);
    const int n = blockIdx.x * 32 + wn * 16 + (lane & 15);

    f32x4 acc = {0.f, 0.f, 0.f, 0.f};
    const float* ar = A32 + (size_t)m * 512;
    const f16* wr = Wf + (size_t)n * 512;
    #pragma unroll 4
    for (int i = 0; i < 16; ++i) {
        int k = i * 32 + quad * 8;
        float4 u0 = *(const float4*)(ar + k);
        float4 u1 = *(const float4*)(ar + k + 4);
        f16x8 av = { (f16)u0.x, (f16)u0.y, (f16)u0.z, (f16)u0.w,
                     (f16)u1.x, (f16)u1.y, (f16)u1.z, (f16)u1.w };
        f16x8 wv = *(const f16x8*)(wr + k);
        acc = MFMA16(av, wv, acc);
    }
    const int col = blockIdx.x * 32 + wn * 16 + (lane & 15);
    #pragma unroll
    for (int r = 0; r < 4; ++r) {
        int row = blockIdx.y * 32 + wb * 16 + quad * 4 + r;
        Cf[(size_t)row * 1024 + col] = (f16)acc[r];
    }
}

// ---------------------------------------------------------------------------
// persistent decoder: 512 WGs x 256 thr (2 WGs/CU), 4 epoch barriers/step.
__global__ __launch_bounds__(256, 2) void decoder_persist(
    const f16* __restrict__ embf16,   // [T][B][512]
    const f16* __restrict__ WB0a,     // [2048][512]  emb-part weights (L2)
    const f16* __restrict__ WB0x,     // [2048][1024] xprev|h0 weights -> LDS
    const f16* __restrict__ WB1p,     // [2048][1024] lstm1 weights -> LDS
    const f16* __restrict__ WoutRf,   // [512][512]   (L2)
    const f16* __restrict__ ctxWV,    // [B*S][1024]
    const float* __restrict__ bsum0, const float* __restrict__ bsum1,
    const float* __restrict__ c0in,   // [2][B][512]
    f16* __restrict__ h0q,            // [T+1][B][512] ring
    f16* __restrict__ h1q,            // [T+1][B][512] ring
    f16* __restrict__ xq,             // [T+1][B][512] ring
    float* __restrict__ scb,          // [B][80]   (uncached path)
    f16* __restrict__ out2b,          // [B][512]  (uncached path)
    unsigned* __restrict__ slots, unsigned* __restrict__ go,
    float* __restrict__ out_outputs, float* __restrict__ out_attn,
    float* __restrict__ out_hT, float* __restrict__ out_cT)
{
    const int wg = blockIdx.x, tid = threadIdx.x;
    const int lane = tid & 63, wv_ = tid >> 6, quad = lane >> 4, m16 = lane & 15;
    const int mslice = wg >> 7;          // 0..3   (32 b rows)
    const int nslice = wg & 127;         // 0..127 (16 gate rows = 4 h dims)
    const int b0 = mslice * 32;
    const int rowbase = nslice * 16;

    __shared__ f16 WLA[16 * 1024];       // xprev|h0 weights, XOR-swizzled
    __shared__ f16 WLB[16 * 1024];       // lstm1 weights
    __shared__ float gbuf[4][32][16];
    __shared__ float scf[80], pp[80];
    __shared__ unsigned o2buf[128];
    __shared__ f16 obuf[256];

    // ---- one-time: weights -> LDS (granule g stored at g ^ (row&7)) ----
    for (int i = tid; i < 2048; i += 256) {
        int r = i >> 7, g = i & 127, gp = g ^ (r & 7);
        *(f16x8*)(WLA + (r * 128 + gp) * 8) =
            *(const f16x8*)(WB0x + ((size_t)(rowbase + r)) * 1024 + g * 8);
        *(f16x8*)(WLB + (r * 128 + gp) * 8) =
            *(const f16x8*)(WB1p + ((size_t)(rowbase + r)) * 1024 + g * 8);
    }
    // cell state registers: thread tid<64 owns (b = tid&31, h = nslice*4 + jp+{0,1})
    const int cb_ = b0 + (tid & 31);
    const int jp = (tid >> 5) * 2;       // 0 or 2 (tid<64)
    const int ch = nslice * 4 + jp;
    float c0r[2], c1r[2], bi0[2][4], bi1[2][4];
    if (tid < 64) {
        #pragma unroll
        for (int j = 0; j < 2; ++j) {
            c0r[j] = c0in[cb_ * 512 + ch + j];
            c1r[j] = c0in[BH + cb_ * 512 + ch + j];
            #pragma unroll
            for (int g = 0; g < 4; ++g) {
                bi0[j][g] = bsum0[g * 512 + ch + j];
                bi1[j][g] = bsum1[g * 512 + ch + j];
            }
        }
    }
    // C1 scores role
    const int b_s = wg >> 2;
    const int soff = (wg & 3) * 20;
    // C1 out2 role (wg < 128)
    const int m2 = wg >> 5, n2 = wg & 31;
    // C2 role (wg < 256)
    const int b2 = wg >> 1, nh = wg & 1;
    unsigned ep = 0;
    __syncthreads();

    for (int t = 0; t < T; ++t) {
        const f16* EMBt = embf16 + (size_t)t * BH;
        const f16* XPt  = xq  + (size_t)t * BH;
        const f16* H0t  = h0q + (size_t)t * BH;
        const f16* H1t  = h1q + (size_t)t * BH;
        f16* H0n = h0q + (size_t)(t + 1) * BH;
        f16* H1n = h1q + (size_t)(t + 1) * BH;
        f16* XPn = xq  + (size_t)(t + 1) * BH;

        // ================= phase A: lstm0 gates, K=1536 k-split over waves ==
        {
            f32x4 ac0 = {0.f, 0.f, 0.f, 0.f}, ac1 = {0.f, 0.f, 0.f, 0.f};
            const int a0r = (b0 + m16) * 512 + quad * 8;
            const int a1r = (b0 + 16 + m16) * 512 + quad * 8;
            const f16* wga = WB0a + (size_t)(rowbase + m16) * 512 + quad * 8;
            const int gq = quad;
            if (wv_ == 0) {                      // emb k 0..384
                #pragma unroll
                for (int ks = 0; ks < 12; ++ks) {
                    int k = ks * 32;
                    f16x8 w = *(const f16x8*)(wga + k);
                    ac0 = MFMA16(*(const f16x8*)(EMBt + a0r + k), w, ac0);
                    ac1 = MFMA16(*(const f16x8*)(EMBt + a1r + k), w, ac1);
                }
            } else if (wv_ == 1) {               // emb 384..512 + xprev 0..256
                #pragma unroll
                for (int ks = 0; ks < 4; ++ks) {
                    int k = 384 + ks * 32;
                    f16x8 w = *(const f16x8*)(wga + k);
                    ac0 = MFMA16(*(const f16x8*)(EMBt + a0r + k), w, ac0);
                    ac1 = MFMA16(*(const f16x8*)(EMBt + a1r + k), w, ac1);
                }
                #pragma unroll
                for (int ks = 0; ks < 8; ++ks) {
                    int k = ks * 32;
                    int gr = (k >> 3) + gq, gp = gr ^ (m16 & 7);
                    f16x8 w = *(const f16x8*)(WLA + (m16 * 128 + gp) * 8);
                    ac0 = MFMA16(*(const f16x8*)(XPt + a0r + k), w, ac0);
                    ac1 = MFMA16(*(const f16x8*)(XPt + a1r + k), w, ac1);
                }
            } else if (wv_ == 2) {               // xprev 256..512 + h0r 0..128
                #pragma unroll
                for (int ks = 0; ks < 8; ++ks) {
                    int k = 256 + ks * 32;
                    int gr = (k >> 3) + gq, gp = gr ^ (m16 & 7);
                    f16x8 w = *(const f16x8*)(WLA + (m16 * 128 + gp) * 8);
                    ac0 = MFMA16(*(const f16x8*)(XPt + a0r + k), w, ac0);
                    ac1 = MFMA16(*(const f16x8*)(XPt + a1r + k), w, ac1);
                }
                #pragma unroll
                for (int ks = 0; ks < 4; ++ks) {
                    int k = ks * 32;
                    int gr = 64 + (k >> 3) + gq, gp = gr ^ (m16 & 7);
                    f16x8 w = *(const f16x8*)(WLA + (m16 * 128 + gp) * 8);
                    ac0 = MFMA16(*(const f16x8*)(H0t + a0r + k), w, ac0);
                    ac1 = MFMA16(*(const f16x8*)(H0t + a1r + k), w, ac1);
                }
            } else {                             // h0r 128..512
                #pragma unroll
                for (int ks = 0; ks < 12; ++ks) {
                    int k = 128 + ks * 32;
                    int gr = 64 + (k >> 3) + gq, gp = gr ^ (m16 & 7);
                    f16x8 w = *(const f16x8*)(WLA + (m16 * 128 + gp) * 8);
                    ac0 = MFMA16(*(const f16x8*)(H0t + a0r + k), w, ac0);
                    ac1 = MFMA16(*(const f16x8*)(H0t + a1r + k), w, ac1);
                }
            }
            #pragma unroll
            for (int r = 0; r < 4; ++r) {
                gbuf[wv_][quad * 4 + r][m16] = ac0[r];
                gbuf[wv_][16 + quad * 4 + r][m16] = ac1[r];
            }
            __syncthreads();
            if (tid < 64) {
                const int bl = tid & 31;
                float hv[2];
                #pragma unroll
                for (int j = 0; j < 2; ++j) {
                    int nl = (jp + j) * 4;
                    float z[4];
                    #pragma unroll
                    for (int g = 0; g < 4; ++g)
                        z[g] = gbuf[0][bl][nl + g] + gbuf[1][bl][nl + g] +
                               gbuf[2][bl][nl + g] + gbuf[3][bl][nl + g] + bi0[j][g];
                    float ig = 1.f / (1.f + expf(-z[0]));
                    float fg = 1.f / (1.f + expf(-z[1]));
                    float gg = tanhf(z[2]);
                    float og = 1.f / (1.f + expf(-z[3]));
                    float c = fg * c0r[j] + ig * gg;
                    c0r[j] = c;
                    hv[j] = og * tanhf(c);
                }
                union { f16 f[2]; unsigned u; } pk;
                pk.f[0] = (f16)hv[0]; pk.f[1] = (f16)hv[1];
                astore4(H0n + cb_ * 512 + ch, pk.u);
                if (t == T - 1) {
                    out_hT[cb_ * 512 + ch] = hv[0];
                    out_hT[cb_ * 512 + ch + 1] = hv[1];
                    out_cT[cb_ * 512 + ch] = c0r[0];
                    out_cT[cb_ * 512 + ch + 1] = c0r[1];
                }
            }
        }
        dbar(slots, go, ++ep, wg);

        // ================= phase B: lstm1 gates, K=1024 =================
        {
            f32x4 ac0 = {0.f, 0.f, 0.f, 0.f}, ac1 = {0.f, 0.f, 0.f, 0.f};
            const int a0r = (b0 + m16) * 512 + quad * 8;
            const int a1r = (b0 + 16 + m16) * 512 + quad * 8;
            const f16* Asrc = (wv_ < 2) ? H0n : H1t;
            const int k0 = (wv_ & 1) * 256;
            const int gbase = ((wv_ < 2) ? 0 : 64) + (k0 >> 3);
            #pragma unroll
            for (int ks = 0; ks < 8; ++ks) {
                int k = k0 + ks * 32;
                int gr = gbase + ks * 4 + quad, gp = gr ^ (m16 & 7);
                f16x8 w = *(const f16x8*)(WLB + (m16 * 128 + gp) * 8);
                ac0 = MFMA16(*(const f16x8*)(Asrc + a0r + k), w, ac0);
                ac1 = MFMA16(*(const f16x8*)(Asrc + a1r + k), w, ac1);
            }
            #pragma unroll
            for (int r = 0; r < 4; ++r) {
                gbuf[wv_][quad * 4 + r][m16] = ac0[r];
                gbuf[wv_][16 + quad * 4 + r][m16] = ac1[r];
            }
            __syncthreads();
            if (tid < 64) {
                const int bl = tid & 31;
                float hv[2];
                #pragma unroll
                for (int j = 0; j < 2; ++j) {
                    int nl = (jp + j) * 4;
                    float z[4];
                    #pragma unroll
                    for (int g = 0; g < 4; ++g)
                        z[g] = gbuf[0][bl][nl + g] + gbuf[1][bl][nl + g] +
                               gbuf[2][bl][nl + g] + gbuf[3][bl][nl + g] + bi1[j][g];
                    float ig = 1.f / (1.f + expf(-z[0]));
                    float fg = 1.f / (1.f + expf(-z[1]));
                    float gg = tanhf(z[2]);
                    float og = 1.f / (1.f + expf(-z[3]));
                    float c = fg * c1r[j] + ig * gg;
                    c1r[j] = c;
                    hv[j] = og * tanhf(c);
                }
                union { f16 f[2]; unsigned u; } pk;
                pk.f[0] = (f16)hv[0]; pk.f[1] = (f16)hv[1];
                astore4(H1n + cb_ * 512 + ch, pk.u);
                if (t == T - 1) {
                    out_hT[BH + cb_ * 512 + ch] = hv[0];
                    out_hT[BH + cb_ * 512 + ch + 1] = hv[1];
                    out_cT[BH + cb_ * 512 + ch] = c1r[0];
                    out_cT[BH + cb_ * 512 + ch + 1] = c1r[1];
                }
            }
        }
        dbar(slots, go, ++ep, wg);

        // ================= phase C1: scores (all) + out2 GEMM (wg<128) =====
        {
            // scores: b_s, s = soff + wv_*5 + i ; 64-lane dot over K=512
            const f16* hrow = H1n + b_s * 512;
            f16x8 hfrag = *(const f16x8*)(hrow + lane * 8);
            #pragma unroll
            for (int i = 0; i < 5; ++i) {
                int s = soff + wv_ * 5 + i;
                const f16* cr = ctxWV + ((size_t)(b_s * 80 + s)) * 1024 + lane * 8;
                f16x8 a = *(const f16x8*)cr;
                float d = 0.f;
                #pragma unroll
                for (int j = 0; j < 8; ++j) d += (float)a[j] * (float)hfrag[j];
                #pragma unroll
                for (int o = 32; o > 0; o >>= 1) d += __shfl_xor(d, o);
                if (lane == 0) astoref(&scb[b_s * 80 + s], d);
            }
            if (wg < 128) {
                // out2[m2*32.., n2*16..] = h1 . WoutR^T, K=512 split over waves
                f32x4 ac0 = {0.f, 0.f, 0.f, 0.f}, ac1 = {0.f, 0.f, 0.f, 0.f};
                const int bb0 = m2 * 32;
                const int a0r = (bb0 + m16) * 512 + quad * 8;
                const int a1r = (bb0 + 16 + m16) * 512 + quad * 8;
                const f16* wr = WoutRf + (size_t)(n2 * 16 + m16) * 512 + quad * 8;
                const int k0 = wv_ * 128;
                #pragma unroll
                for (int ks = 0; ks < 4; ++ks) {
                    int k = k0 + ks * 32;
                    f16x8 w = *(const f16x8*)(wr + k);
                    ac0 = MFMA16(*(const f16x8*)(H1n + a0r + k), w, ac0);
                    ac1 = MFMA16(*(const f16x8*)(H1n + a1r + k), w, ac1);
                }
                __syncthreads();
                #pragma unroll
                for (int r = 0; r < 4; ++r) {
                    gbuf[wv_][quad * 4 + r][m16] = ac0[r];
                    gbuf[wv_][16 + quad * 4 + r][m16] = ac1[r];
                }
                __syncthreads();
                // 256 threads: (b = tid>>3, npair = (tid&7)*2)
                const int bl = tid >> 3, np = (tid & 7) * 2;
                float v0 = gbuf[0][bl][np] + gbuf[1][bl][np] + gbuf[2][bl][np] + gbuf[3][bl][np];
                float v1 = gbuf[0][bl][np+1] + gbuf[1][bl][np+1] + gbuf[2][bl][np+1] + gbuf[3][bl][np+1];
                union { f16 f[2]; unsigned u; } pk;
                pk.f[0] = (f16)v0; pk.f[1] = (f16)v1;
                astore4(out2b + (bb0 + bl) * 512 + n2 * 16 + np, pk.u);
            }
        }
        dbar(slots, go, ++ep, wg);

        // ================= phase C2: softmax + ctxV reduce + out (wg<256) ==
        if (wg < 256) {
            if (wv_ == 0 && lane < 40) {
                union { u64 u; float f[2]; } v;
                v.u = aload8(&scb[b2 * 80 + lane * 2]);
                scf[lane * 2] = v.f[0];
                scf[lane * 2 + 1] = v.f[1];
            }
            if (tid < 128)
                o2buf[tid] = aload4((const unsigned*)(out2b + b2 * 512 + nh * 256) + tid);
            __syncthreads();
            if (wv_ == 0) {
                float e0 = scf[lane];
                float e1 = (lane < 16) ? scf[64 + lane] : -1e30f;
                float m = fmaxf(e0, e1);
                #pragma unroll
                for (int o = 32; o > 0; o >>= 1) m = fmaxf(m, __shfl_xor(m, o));
                float x0 = expf(e0 - m);
                float x1 = (lane < 16) ? expf(e1 - m) : 0.f;
                float su = x0 + x1;
                #pragma unroll
                for (int o = 32; o > 0; o >>= 1) su += __shfl_xor(su, o);
                float inv = 1.f / su;
                float p0 = x0 * inv;
                pp[lane] = p0;
                if (nh == 0) out_attn[((size_t)t * 128 + b2) * 80 + lane] = p0;
                if (lane < 16) {
                    float p1 = x1 * inv;
                    pp[64 + lane] = p1;
                    if (nh == 0) out_attn[((size_t)t * 128 + b2) * 80 + 64 + lane] = p1;
                }
            }
            __syncthreads();
            const int n = nh * 256 + tid;
            float acc = 0.f;
            const f16* cv = ctxWV + (size_t)b2 * 80 * 1024 + 512 + n;
            #pragma unroll 8
            for (int s = 0; s < 80; ++s) acc += pp[s] * (float)cv[(size_t)s * 1024];
            float o2 = (float)((const f16*)o2buf)[tid];
            float o = tanhf(acc + o2);
            out_outputs[(size_t)t * BH + b2 * 512 + n] = o;
            obuf[tid] = (f16)o;
            __syncthreads();
            if (tid < 64)
                astore8(XPn + b2 * 512 + nh * 256 + tid * 4, ((const u64*)obuf)[tid]);
        }
        dbar(slots, go, ++ep, wg);
    }
}

// ---------------------------------------------------------------------------
extern "C" void kernel_launch(void* const* d_in, const int* in_sizes, int n_in,
                              void* d_out, int out_size, void* d_ws, size_t ws_size,
                              hipStream_t stream)
{
    const int*   tokens  = (const int*)  d_in[0];
    const float* h0      = (const float*)d_in[1];
    const float* c0      = (const float*)d_in[2];
    const float* context = (const float*)d_in[3];
    const float* embtab  = (const float*)d_in[4];
    const float* Wih0    = (const float*)d_in[5];
    const float* Whh0    = (const float*)d_in[6];
    const float* bih0    = (const float*)d_in[7];
    const float* bhh0    = (const float*)d_in[8];
    const float* Wih1    = (const float*)d_in[9];
    const float* Whh1    = (const float*)d_in[10];
    const float* bih1    = (const float*)d_in[11];
    const float* bhh1    = (const float*)d_in[12];
    const float* Win     = (const float*)d_in[13];
    const float* Wout    = (const float*)d_in[14];

    float* outF        = (float*)d_out;
    float* out_outputs = outF;
    float* out_hT      = outF + (size_t)T * BH;
    float* out_cT      = out_hT + 2 * BH;
    float* out_attn    = out_cT + 2 * BH;

    char* w = (char*)d_ws;
    auto alloc = [&](size_t bytes) {
        char* p = w;
        w += (bytes + 255) & ~(size_t)255;
        return p;
    };
    f16*      WB0a   = (f16*)     alloc((size_t)2048 * 512 * 2);
    f16*      WB0x   = (f16*)     alloc((size_t)2048 * 1024 * 2);
    f16*      WB1p   = (f16*)     alloc((size_t)2048 * 1024 * 2);
    f16*      WoutRf = (f16*)     alloc((size_t)512 * 512 * 2);
    f16*      WcatT  = (f16*)     alloc((size_t)1024 * 512 * 2);
    f16*      embf16 = (f16*)     alloc((size_t)T * B * 512 * 2);
    f16*      ctxWV  = (f16*)     alloc((size_t)B * S * 1024 * 2);
    float*    bsum0  = (float*)   alloc(2048 * 4);
    float*    bsum1  = (float*)   alloc(2048 * 4);
    f16*      h0q    = (f16*)     alloc((size_t)(T + 1) * BH * 2);
    f16*      h1q    = (f16*)     alloc((size_t)(T + 1) * BH * 2);
    f16*      xq     = (f16*)     alloc((size_t)(T + 1) * BH * 2);
    float*    scb    = (float*)   alloc((size_t)B * 80 * 4);
    f16*      out2b  = (f16*)     alloc((size_t)B * 512 * 2);
    unsigned* slots  = (unsigned*)alloc(2048 * 4);
    unsigned* go     = (unsigned*)alloc(256 * 4);

    prep_all<<<1024, 256, 0, stream>>>(Wih0, Whh0, Wih1, Whh1, Wout, Win,
                                       bih0, bhh0, bih1, bhh1, h0,
                                       WB0a, WB0x, WB1p, WoutRf, WcatT,
                                       bsum0, bsum1, h0q, h1q, xq, slots, go);
    prep_emb<<<2048, 256, 0, stream>>>(tokens, embtab, embf16);
    gemm_ctx<<<dim3(32, 320), 256, 0, stream>>>(context, WcatT, ctxWV);

    decoder_persist<<<NWG, 256, 0, stream>>>(
        embf16, WB0a, WB0x, WB1p, WoutRf, ctxWV, bsum0, bsum1, c0,
        h0q, h1q, xq, scb, out2b, slots, go,
        out_outputs, out_attn, out_hT, out_cT);
}